// Round 1
// baseline (789.915 us; speedup 1.0000x reference)
//
#include <hip/hip_runtime.h>

typedef __bf16 bf16x8 __attribute__((ext_vector_type(8)));
typedef __bf16 bf16x4 __attribute__((ext_vector_type(4)));
typedef float  f32x4  __attribute__((ext_vector_type(4)));

constexpr int Bc = 2, Sc = 256, Kc = 32, Tc = 8192, Dc = 1024, Vc = 6144, NLc = 4;
constexpr int SEG = 256, WARM = 64, NSEG = Tc / SEG;

// ---------------------------------------------------------------------------
// GEMM: C[M][N] (f32) = A[M][K] (bf16, row-major) x BT[N][K] (bf16, row-major)
// 128x128 tile, BK=64, 4 waves (2x2), each wave 64x64 via 4x4 mfma 16x16x32.
// LDS XOR-swizzled (byte ^= (row&7)<<4) -> conflict-free b128 reads & writes.
// EPI 0: C = acc           EPI 1: resid += acc; xbf = bf16(resid)
// EPI 2: C = acc + bias[col]
// ---------------------------------------------------------------------------
template<int EPI>
__global__ __launch_bounds__(256)
void gemm_bt(const __bf16* __restrict__ A, const __bf16* __restrict__ BT,
             int M, int N, int Kd,
             float* __restrict__ Cout, float* __restrict__ resid,
             __bf16* __restrict__ xbf, const float* __restrict__ bias)
{
    __shared__ char lds[32768];
    char* As = lds;
    char* Bs = lds + 16384;
    const int tid  = threadIdx.x;
    const int lane = tid & 63;
    const int wid  = tid >> 6;
    const int wm   = wid & 1, wn = wid >> 1;
    const int bm   = blockIdx.y * 128, bn = blockIdx.x * 128;

    f32x4 acc[4][4] = {};

    for (int kt = 0; kt < Kd; kt += 64) {
#pragma unroll
        for (int i = 0; i < 4; ++i) {
            int chunk = tid + i * 256;          // 1024 chunks of 8 bf16 (16B)
            int row = chunk >> 3, kc = chunk & 7;
            int sw  = (kc * 16) ^ ((row & 7) << 4);
            f32x4 av = *(const f32x4*)(A  + (size_t)(bm + row) * Kd + kt + kc * 8);
            *(f32x4*)(As + row * 128 + sw) = av;
            f32x4 bv = *(const f32x4*)(BT + (size_t)(bn + row) * Kd + kt + kc * 8);
            *(f32x4*)(Bs + row * 128 + sw) = bv;
        }
        __syncthreads();
#pragma unroll
        for (int kk = 0; kk < 2; ++kk) {
            const int ko = kk * 64 + ((lane >> 4) << 4);   // k-byte offset in row
            bf16x8 af[4], bfr[4];
#pragma unroll
            for (int mi = 0; mi < 4; ++mi) {
                int row = wm * 64 + mi * 16 + (lane & 15);
                af[mi] = *(const bf16x8*)(As + row * 128 + (ko ^ ((row & 7) << 4)));
            }
#pragma unroll
            for (int ni = 0; ni < 4; ++ni) {
                int row = wn * 64 + ni * 16 + (lane & 15);
                bfr[ni] = *(const bf16x8*)(Bs + row * 128 + (ko ^ ((row & 7) << 4)));
            }
#pragma unroll
            for (int mi = 0; mi < 4; ++mi)
#pragma unroll
                for (int ni = 0; ni < 4; ++ni)
                    acc[mi][ni] = __builtin_amdgcn_mfma_f32_16x16x32_bf16(
                        af[mi], bfr[ni], acc[mi][ni], 0, 0, 0);
        }
        __syncthreads();
    }

    const int cc = lane & 15, cr = (lane >> 4) * 4;   // C/D: col=lane&15, row=(lane>>4)*4+r
#pragma unroll
    for (int mi = 0; mi < 4; ++mi) {
#pragma unroll
        for (int ni = 0; ni < 4; ++ni) {
            int gcol = bn + wn * 64 + ni * 16 + cc;
#pragma unroll
            for (int r = 0; r < 4; ++r) {
                int grow = bm + wm * 64 + mi * 16 + cr + r;
                size_t idx = (size_t)grow * N + gcol;
                float v = acc[mi][ni][r];
                if (EPI == 0) {
                    Cout[idx] = v;
                } else if (EPI == 1) {
                    float nx = resid[idx] + v;
                    resid[idx] = nx;
                    xbf[idx] = (__bf16)nx;
                } else {
                    Cout[idx] = v + bias[gcol];
                }
            }
        }
    }
}

// ---------------------------------------------------------------------------
// PLIF scan per chain (b,e): V = beta*V + u[t]; spike -> bf16(vth) or 0.
// Segments of SEG steps with WARM redundant warm-up (beta=0.5 -> 0.5^64 ~ 0).
// TOKEN_U=1: u has one row per token (layer-1 structural optimization).
// ---------------------------------------------------------------------------
template<int TOKEN_U>
__global__ __launch_bounds__(256)
void layer_scan(const float* __restrict__ u, const float* __restrict__ beta,
                const float* __restrict__ vth, __bf16* __restrict__ spk)
{
    const int e = blockIdx.x * 256 + threadIdx.x;
    const int b = blockIdx.y;
    const int seg = blockIdx.z;
    const float bet = beta[e];
    const float vt  = vth[e];
    const __bf16 vtb = (__bf16)vt;
    const __bf16 zb  = (__bf16)0.0f;
    float V = 0.0f;
    const int t0 = seg * SEG;
    if (seg != 0) {
        for (int t = t0 - WARM; t < t0; ++t) {
            size_t r = TOKEN_U ? ((size_t)(t >> 5) * Bc + b) : ((size_t)t * Bc + b);
            V = fmaf(bet, V, u[r * Dc + e]);
        }
    }
    for (int t = t0; t < t0 + SEG; ++t) {
        size_t r = TOKEN_U ? ((size_t)(t >> 5) * Bc + b) : ((size_t)t * Bc + b);
        V = fmaf(bet, V, u[r * Dc + e]);
        spk[((size_t)t * Bc + b) * Dc + e] = (V >= vt) ? vtb : zb;
    }
}

// Output PLIF scan fused with K-frame mean -> decoded[b][s][d] (bf16)
__global__ __launch_bounds__(256)
void out_scan(const float* __restrict__ h, const float* __restrict__ alpha_p,
              const float* __restrict__ beta, const float* __restrict__ vth,
              __bf16* __restrict__ decoded)
{
    const int d = blockIdx.x * 256 + threadIdx.x;
    const int b = blockIdx.y;
    const int seg = blockIdx.z;
    const float al  = alpha_p[0];
    const float bet = beta[d];
    const float vt  = vth[d];
    float V = 0.0f;
    const int t0 = seg * SEG;
    if (seg != 0) {
        for (int t = t0 - WARM; t < t0; ++t)
            V = fmaf(bet, V, al * h[((size_t)t * Bc + b) * Dc + d]);
    }
    for (int tok = 0; tok < SEG / Kc; ++tok) {
        float sum = 0.0f;
#pragma unroll
        for (int k2 = 0; k2 < Kc; ++k2) {
            int t = t0 + tok * Kc + k2;
            V = fmaf(bet, V, al * h[((size_t)t * Bc + b) * Dc + d]);
            sum += (V >= vt) ? vt : 0.0f;
        }
        int s = t0 / Kc + tok;
        decoded[((size_t)b * Sc + s) * Dc + d] = (__bf16)(sum * (1.0f / 32.0f));
    }
}

// RMSNorm over D=1024 per row; one block (256 thr x float4) per row.
template<int OUT_BF16>
__global__ __launch_bounds__(256)
void rmsnorm_rows(const float* __restrict__ in, const float* __restrict__ w,
                  float* __restrict__ outf, __bf16* __restrict__ outb)
{
    const int r = blockIdx.x;
    const int tid = threadIdx.x;
    const f32x4 v = ((const f32x4*)(in + (size_t)r * Dc))[tid];
    float ss = v[0]*v[0] + v[1]*v[1] + v[2]*v[2] + v[3]*v[3];
#pragma unroll
    for (int off = 32; off >= 1; off >>= 1)
        ss += __shfl_down(ss, off);
    __shared__ float red[4];
    if ((tid & 63) == 0) red[tid >> 6] = ss;
    __syncthreads();
    float tot = red[0] + red[1] + red[2] + red[3];
    float sc = rsqrtf(tot * (1.0f / Dc) + 1e-6f);
    const f32x4 wv = ((const f32x4*)w)[tid];
    float o0 = v[0]*sc*wv[0], o1 = v[1]*sc*wv[1], o2 = v[2]*sc*wv[2], o3 = v[3]*sc*wv[3];
    if (OUT_BF16) {
        bf16x4 o; o[0]=(__bf16)o0; o[1]=(__bf16)o1; o[2]=(__bf16)o2; o[3]=(__bf16)o3;
        ((bf16x4*)(outb + (size_t)r * Dc))[tid] = o;
    } else {
        f32x4 o = {o0, o1, o2, o3};
        ((f32x4*)(outf + (size_t)r * Dc))[tid] = o;
    }
}

// Embed gather -> x_f32 (per frame rows r=t*B+b) + bf16 token rows (r=s*B+b)
__global__ __launch_bounds__(256)
void encode(const int* __restrict__ tok, const float* __restrict__ embed,
            float* __restrict__ x, __bf16* __restrict__ xtok)
{
    const int t = blockIdx.x, b = blockIdx.y, tid = threadIdx.x;
    const int s = t >> 5;
    const int id = tok[b * Sc + s];
    const f32x4 v = ((const f32x4*)(embed + (size_t)id * Dc))[tid];
    ((f32x4*)(x + ((size_t)t * Bc + b) * Dc))[tid] = v;
    if ((t & 31) == 0) {
        bf16x4 o; o[0]=(__bf16)v[0]; o[1]=(__bf16)v[1]; o[2]=(__bf16)v[2]; o[3]=(__bf16)v[3];
        ((bf16x4*)(xtok + ((size_t)s * Bc + b) * Dc))[tid] = o;
    }
}

// W (D x D, f32) -> W^T (D x D, bf16); 32x32 LDS tiles, blockIdx.z = matrix id
__global__ __launch_bounds__(256)
void transpose_cast(const float* __restrict__ Ws, __bf16* __restrict__ Wd)
{
    __shared__ float tile[32][33];
    const float* Wm = Ws + (size_t)blockIdx.z * Dc * Dc;
    __bf16*      Wo = Wd + (size_t)blockIdx.z * Dc * Dc;
    const int tx = threadIdx.x, ty = threadIdx.y;
    const int d0 = blockIdx.x * 32, e0 = blockIdx.y * 32;
#pragma unroll
    for (int i = 0; i < 4; ++i)
        tile[ty + i*8][tx] = Wm[(size_t)(d0 + ty + i*8) * Dc + e0 + tx];
    __syncthreads();
#pragma unroll
    for (int i = 0; i < 4; ++i)
        Wo[(size_t)(e0 + ty + i*8) * Dc + d0 + tx] = (__bf16)tile[tx][ty + i*8];
}

__global__ __launch_bounds__(256)
void cast_bf16_k(const float* __restrict__ in, __bf16* __restrict__ out, int n4)
{
    int i = blockIdx.x * 256 + threadIdx.x;
    if (i >= n4) return;
    f32x4 v = ((const f32x4*)in)[i];
    bf16x4 o; o[0]=(__bf16)v[0]; o[1]=(__bf16)v[1]; o[2]=(__bf16)v[2]; o[3]=(__bf16)v[3];
    ((bf16x4*)out)[i] = o;
}

// ---------------------------------------------------------------------------
extern "C" void kernel_launch(void* const* d_in, const int* in_sizes, int n_in,
                              void* d_out, int out_size, void* d_ws, size_t ws_size,
                              hipStream_t stream)
{
    const int*   token_ids  = (const int*)  d_in[0];
    const float* embed      = (const float*)d_in[1];
    const float* W_in       = (const float*)d_in[2];
    const float* W_out      = (const float*)d_in[3];
    const float* layer_beta = (const float*)d_in[4];
    const float* layer_vth  = (const float*)d_in[5];
    const float* out_norm_w = (const float*)d_in[6];
    const float* out_beta   = (const float*)d_in[7];
    const float* out_vth    = (const float*)d_in[8];
    const float* out_alpha  = (const float*)d_in[9];
    const float* decode_w   = (const float*)d_in[10];
    const float* decode_b   = (const float*)d_in[11];
    const float* li_norm_w  = (const float*)d_in[12];
    float* out = (float*)d_out;

    // workspace carve-up (~237 MB)
    size_t off = 0;
    auto alloc = [&](size_t bytes) -> void* {
        void* p = (char*)d_ws + off;
        off += (bytes + 255) & ~(size_t)255;
        return p;
    };
    float*  x_f32   = (float*) alloc((size_t)Tc * Bc * Dc * 4);
    float*  u_f32   = (float*) alloc((size_t)Tc * Bc * Dc * 4);   // reused as h
    __bf16* x_bf    = (__bf16*)alloc((size_t)Tc * Bc * Dc * 2);
    __bf16* spk     = (__bf16*)alloc((size_t)Tc * Bc * Dc * 2);
    __bf16* wT_in   = (__bf16*)alloc((size_t)NLc * Dc * Dc * 2);
    __bf16* wT_out  = (__bf16*)alloc((size_t)NLc * Dc * Dc * 2);
    __bf16* emb_bf  = (__bf16*)alloc((size_t)Vc * Dc * 2);
    __bf16* decw_bf = (__bf16*)alloc((size_t)Dc * Dc * 2);
    __bf16* xtok    = (__bf16*)alloc((size_t)Bc * Sc * Dc * 2);
    __bf16* decoded = (__bf16*)alloc((size_t)Bc * Sc * Dc * 2);
    float*  h2      = (float*) alloc((size_t)Bc * Sc * Dc * 4);
    __bf16* h2n     = (__bf16*)alloc((size_t)Bc * Sc * Dc * 2);

    // weight prep
    transpose_cast<<<dim3(32, 32, NLc), dim3(32, 8), 0, stream>>>(W_in,  wT_in);
    transpose_cast<<<dim3(32, 32, NLc), dim3(32, 8), 0, stream>>>(W_out, wT_out);
    cast_bf16_k<<<(Vc * Dc / 4 + 255) / 256, 256, 0, stream>>>(embed, emb_bf, Vc * Dc / 4);
    cast_bf16_k<<<(Dc * Dc / 4 + 255) / 256, 256, 0, stream>>>(decode_w, decw_bf, Dc * Dc / 4);

    // encode
    encode<<<dim3(Tc, Bc), 256, 0, stream>>>(token_ids, embed, x_f32, xtok);

    // layer 0 (token-level u GEMM: 32x less work)
    gemm_bt<0><<<dim3(Dc / 128, (Bc * Sc) / 128), 256, 0, stream>>>(
        xtok, wT_in, Bc * Sc, Dc, Dc, u_f32, nullptr, nullptr, nullptr);
    layer_scan<1><<<dim3(Dc / 256, Bc, NSEG), 256, 0, stream>>>(
        u_f32, layer_beta, layer_vth, spk);
    gemm_bt<1><<<dim3(Dc / 128, (Tc * Bc) / 128), 256, 0, stream>>>(
        spk, wT_out, Tc * Bc, Dc, Dc, nullptr, x_f32, x_bf, nullptr);

    // layers 1..3
    for (int l = 1; l < NLc; ++l) {
        gemm_bt<0><<<dim3(Dc / 128, (Tc * Bc) / 128), 256, 0, stream>>>(
            x_bf, wT_in + (size_t)l * Dc * Dc, Tc * Bc, Dc, Dc, u_f32,
            nullptr, nullptr, nullptr);
        layer_scan<0><<<dim3(Dc / 256, Bc, NSEG), 256, 0, stream>>>(
            u_f32, layer_beta + (size_t)l * Dc, layer_vth + (size_t)l * Dc, spk);
        gemm_bt<1><<<dim3(Dc / 128, (Tc * Bc) / 128), 256, 0, stream>>>(
            spk, wT_out + (size_t)l * Dc * Dc, Tc * Bc, Dc, Dc, nullptr,
            x_f32, x_bf, nullptr);
    }

    // decode head
    rmsnorm_rows<0><<<Tc * Bc, 256, 0, stream>>>(x_f32, out_norm_w, u_f32, nullptr);
    out_scan<<<dim3(Dc / 256, Bc, NSEG), 256, 0, stream>>>(
        u_f32, out_alpha, out_beta, out_vth, decoded);
    gemm_bt<2><<<dim3(Dc / 128, (Bc * Sc) / 128), 256, 0, stream>>>(
        decoded, decw_bf, Bc * Sc, Dc, Dc, h2, nullptr, nullptr, decode_b);
    rmsnorm_rows<1><<<Bc * Sc, 256, 0, stream>>>(h2, li_norm_w, nullptr, h2n);
    gemm_bt<0><<<dim3(Vc / 128, (Bc * Sc) / 128), 256, 0, stream>>>(
        h2n, emb_bf, Bc * Sc, Vc, Dc, out, nullptr, nullptr, nullptr);
}

// Round 2
// 456.743 us; speedup vs baseline: 1.7295x; 1.7295x over previous
//
#include <hip/hip_runtime.h>

typedef __bf16 bf16x8 __attribute__((ext_vector_type(8)));
typedef __bf16 bf16x4 __attribute__((ext_vector_type(4)));
typedef float  f32x4  __attribute__((ext_vector_type(4)));

constexpr int Bc = 2, Sc = 256, Kc = 32, Tc = 8192, Dc = 1024, Vc = 6144, NLc = 4;
constexpr int SEG = 256, WARM = 64, NSEG = Tc / SEG;
constexpr int NPANEL = (Tc * Bc) / 128;   // 128 row-panels of the big GEMMs

__device__ __forceinline__ void gload16(const void* g, void* l) {
    __builtin_amdgcn_global_load_lds(
        (const __attribute__((address_space(1))) unsigned int*)g,
        (__attribute__((address_space(3))) unsigned int*)l,
        16, 0, 0);
}

// bijective XCD-aware block swizzle (m204 variant)
__device__ __forceinline__ int xcd_swz(int lin, int nwg) {
    int q = nwg >> 3, r = nwg & 7;
    int x = lin & 7, o = lin >> 3;
    int base = (x < r) ? x * (q + 1) : r * (q + 1) + (x - r) * q;
    return base + o;
}

// ---------------------------------------------------------------------------
// GEMM: C[M][N] = A[M][K] (bf16 rm) x BT[N][K] (bf16 rm), 128x128 tile, BK=64,
// 4 waves (2x2), 4x4 mfma 16x16x32. LDS XOR-swizzle via pre-swizzled global
// source + linear-dest global_load_lds (width 16).
// EPI 0: Cout(f32)=acc   EPI 1: resid+=acc; outb=bf16(resid)  [panel skip]
// EPI 2: Cout=acc+bias   EPI 3: outb=bf16(acc)
// ---------------------------------------------------------------------------
template<int EPI>
__global__ __launch_bounds__(256)
void gemm_bt(const __bf16* __restrict__ A, const __bf16* __restrict__ BT,
             int M, int N, int Kd,
             float* __restrict__ Cout, float* __restrict__ resid,
             __bf16* __restrict__ outb, const float* __restrict__ bias,
             const int* __restrict__ flags)
{
    __shared__ char lds[32768];
    char* As = lds;
    char* Bs = lds + 16384;
    const int tid  = threadIdx.x;
    const int lane = tid & 63;
    const int wid  = tid >> 6;
    const int wm   = wid & 1, wn = wid >> 1;

    const int nwg = gridDim.x * gridDim.y;
    const int lin = blockIdx.y * gridDim.x + blockIdx.x;
    const int swz = xcd_swz(lin, nwg);
    const int bn  = (swz % gridDim.x) * 128;
    const int bm  = (swz / gridDim.x) * 128;

    if (EPI == 1 && flags[bm >> 7] == 0) return;   // zero spike panel -> no-op

    f32x4 acc[4][4] = {};

    for (int kt = 0; kt < Kd; kt += 64) {
#pragma unroll
        for (int i = 0; i < 4; ++i) {
            int chunk = i * 256 + tid;            // 1024 chunks of 16B
            int row = chunk >> 3, kc = chunk & 7;
            int kcs = kc ^ (row & 7);             // pre-swizzled global source
            gload16(A  + (size_t)(bm + row) * Kd + kt + kcs * 8, As + chunk * 16);
            gload16(BT + (size_t)(bn + row) * Kd + kt + kcs * 8, Bs + chunk * 16);
        }
        __syncthreads();
#pragma unroll
        for (int kk = 0; kk < 2; ++kk) {
            const int ko = kk * 64 + ((lane >> 4) << 4);
            bf16x8 af[4], bfr[4];
#pragma unroll
            for (int mi = 0; mi < 4; ++mi) {
                int row = wm * 64 + mi * 16 + (lane & 15);
                af[mi] = *(const bf16x8*)(As + row * 128 + (ko ^ ((row & 7) << 4)));
            }
#pragma unroll
            for (int ni = 0; ni < 4; ++ni) {
                int row = wn * 64 + ni * 16 + (lane & 15);
                bfr[ni] = *(const bf16x8*)(Bs + row * 128 + (ko ^ ((row & 7) << 4)));
            }
#pragma unroll
            for (int mi = 0; mi < 4; ++mi)
#pragma unroll
                for (int ni = 0; ni < 4; ++ni)
                    acc[mi][ni] = __builtin_amdgcn_mfma_f32_16x16x32_bf16(
                        af[mi], bfr[ni], acc[mi][ni], 0, 0, 0);
        }
        __syncthreads();
    }

    const int cc = lane & 15, cr = (lane >> 4) * 4;
#pragma unroll
    for (int mi = 0; mi < 4; ++mi) {
#pragma unroll
        for (int ni = 0; ni < 4; ++ni) {
            int gcol = bn + wn * 64 + ni * 16 + cc;
#pragma unroll
            for (int r = 0; r < 4; ++r) {
                int grow = bm + wm * 64 + mi * 16 + cr + r;
                size_t idx = (size_t)grow * N + gcol;
                float v = acc[mi][ni][r];
                if (EPI == 0) {
                    Cout[idx] = v;
                } else if (EPI == 1) {
                    float nx = resid[idx] + v;
                    resid[idx] = nx;
                    outb[idx] = (__bf16)nx;
                } else if (EPI == 2) {
                    Cout[idx] = v + bias[gcol];
                } else {
                    outb[idx] = (__bf16)v;
                }
            }
        }
    }
}

// ---------------------------------------------------------------------------
// PLIF scan per chain (b,e): V = beta*V + u[t]; spike -> bf16(vth) or 0.
// Segments of SEG with WARM warm-up. Records per-64-frame-panel spike flags.
// TOKEN_U=1: u has one row per token (layer-0 structural optimization).
// ---------------------------------------------------------------------------
template<int TOKEN_U>
__global__ __launch_bounds__(256)
void layer_scan(const __bf16* __restrict__ u, const float* __restrict__ beta,
                const float* __restrict__ vth, __bf16* __restrict__ spk,
                int* __restrict__ flags)
{
    const int e = blockIdx.x * 256 + threadIdx.x;
    const int b = blockIdx.y;
    const int seg = blockIdx.z;
    const int lane = threadIdx.x & 63;
    const float bet = beta[e];
    const float vt  = vth[e];
    const __bf16 vtb = (__bf16)vt;
    const __bf16 zb  = (__bf16)0.0f;
    float V = 0.0f;
    const int t0 = seg * SEG;
    if (seg != 0) {
        for (int t = t0 - WARM; t < t0; ++t) {
            size_t r = TOKEN_U ? ((size_t)(t >> 5) * Bc + b) : ((size_t)t * Bc + b);
            V = fmaf(bet, V, (float)u[r * Dc + e]);
        }
    }
    unsigned anyv = 0;
    for (int t = t0; t < t0 + SEG; ++t) {
        size_t r = TOKEN_U ? ((size_t)(t >> 5) * Bc + b) : ((size_t)t * Bc + b);
        V = fmaf(bet, V, (float)u[r * Dc + e]);
        bool sp = (V >= vt);
        if (sp) anyv |= 1u << ((t - t0) >> 6);
        spk[((size_t)t * Bc + b) * Dc + e] = sp ? vtb : zb;
    }
#pragma unroll
    for (int j = 0; j < SEG / 64; ++j) {
        if (__any(anyv & (1u << j)) && lane == 0)
            atomicOr(&flags[(t0 >> 6) + j], 1);
    }
}

// Output PLIF scan fused with K-frame mean -> decoded[b][s][d] (bf16)
__global__ __launch_bounds__(256)
void out_scan(const float* __restrict__ h, const float* __restrict__ alpha_p,
              const float* __restrict__ beta, const float* __restrict__ vth,
              __bf16* __restrict__ decoded)
{
    const int d = blockIdx.x * 256 + threadIdx.x;
    const int b = blockIdx.y;
    const int seg = blockIdx.z;
    const float al  = alpha_p[0];
    const float bet = beta[d];
    const float vt  = vth[d];
    float V = 0.0f;
    const int t0 = seg * SEG;
    if (seg != 0) {
        for (int t = t0 - WARM; t < t0; ++t)
            V = fmaf(bet, V, al * h[((size_t)t * Bc + b) * Dc + d]);
    }
    for (int tok = 0; tok < SEG / Kc; ++tok) {
        float sum = 0.0f;
#pragma unroll
        for (int k2 = 0; k2 < Kc; ++k2) {
            int t = t0 + tok * Kc + k2;
            V = fmaf(bet, V, al * h[((size_t)t * Bc + b) * Dc + d]);
            sum += (V >= vt) ? vt : 0.0f;
        }
        int s = t0 / Kc + tok;
        decoded[((size_t)b * Sc + s) * Dc + d] = (__bf16)(sum * (1.0f / 32.0f));
    }
}

// RMSNorm over D=1024 per row; one block (256 thr x float4) per row. In-place safe.
template<int OUT_BF16>
__global__ __launch_bounds__(256)
void rmsnorm_rows(const float* __restrict__ in, const float* __restrict__ w,
                  float* __restrict__ outf, __bf16* __restrict__ outb)
{
    const int r = blockIdx.x;
    const int tid = threadIdx.x;
    const f32x4 v = ((const f32x4*)(in + (size_t)r * Dc))[tid];
    float ss = v[0]*v[0] + v[1]*v[1] + v[2]*v[2] + v[3]*v[3];
#pragma unroll
    for (int off = 32; off >= 1; off >>= 1)
        ss += __shfl_down(ss, off);
    __shared__ float red[4];
    if ((tid & 63) == 0) red[tid >> 6] = ss;
    __syncthreads();
    float tot = red[0] + red[1] + red[2] + red[3];
    float sc = rsqrtf(tot * (1.0f / Dc) + 1e-6f);
    const f32x4 wv = ((const f32x4*)w)[tid];
    float o0 = v[0]*sc*wv[0], o1 = v[1]*sc*wv[1], o2 = v[2]*sc*wv[2], o3 = v[3]*sc*wv[3];
    if (OUT_BF16) {
        bf16x4 o; o[0]=(__bf16)o0; o[1]=(__bf16)o1; o[2]=(__bf16)o2; o[3]=(__bf16)o3;
        ((bf16x4*)(outb + (size_t)r * Dc))[tid] = o;
    } else {
        f32x4 o = {o0, o1, o2, o3};
        ((f32x4*)(outf + (size_t)r * Dc))[tid] = o;
    }
}

// Embed gather -> x_f32 + x_bf (all frames) + xtok (token rows, bf16)
__global__ __launch_bounds__(256)
void encode(const int* __restrict__ tok, const float* __restrict__ embed,
            float* __restrict__ x, __bf16* __restrict__ xbf,
            __bf16* __restrict__ xtok)
{
    const int t = blockIdx.x, b = blockIdx.y, tid = threadIdx.x;
    const int s = t >> 5;
    const int id = tok[b * Sc + s];
    const f32x4 v = ((const f32x4*)(embed + (size_t)id * Dc))[tid];
    ((f32x4*)(x + ((size_t)t * Bc + b) * Dc))[tid] = v;
    bf16x4 o; o[0]=(__bf16)v[0]; o[1]=(__bf16)v[1]; o[2]=(__bf16)v[2]; o[3]=(__bf16)v[3];
    ((bf16x4*)(xbf + ((size_t)t * Bc + b) * Dc))[tid] = o;
    if ((t & 31) == 0)
        ((bf16x4*)(xtok + ((size_t)s * Bc + b) * Dc))[tid] = o;
}

// W (D x D, f32) -> W^T (D x D, bf16); 32x32 LDS tiles, blockIdx.z = matrix id
__global__ __launch_bounds__(256)
void transpose_cast(const float* __restrict__ Ws, __bf16* __restrict__ Wd)
{
    __shared__ float tile[32][33];
    const float* Wm = Ws + (size_t)blockIdx.z * Dc * Dc;
    __bf16*      Wo = Wd + (size_t)blockIdx.z * Dc * Dc;
    const int tx = threadIdx.x, ty = threadIdx.y;
    const int d0 = blockIdx.x * 32, e0 = blockIdx.y * 32;
#pragma unroll
    for (int i = 0; i < 4; ++i)
        tile[ty + i*8][tx] = Wm[(size_t)(d0 + ty + i*8) * Dc + e0 + tx];
    __syncthreads();
#pragma unroll
    for (int i = 0; i < 4; ++i)
        Wo[(size_t)(e0 + ty + i*8) * Dc + d0 + tx] = (__bf16)tile[tx][ty + i*8];
}

__global__ __launch_bounds__(256)
void cast_bf16_k(const float* __restrict__ in, __bf16* __restrict__ out, int n4)
{
    int i = blockIdx.x * 256 + threadIdx.x;
    if (i >= n4) return;
    f32x4 v = ((const f32x4*)in)[i];
    bf16x4 o; o[0]=(__bf16)v[0]; o[1]=(__bf16)v[1]; o[2]=(__bf16)v[2]; o[3]=(__bf16)v[3];
    ((bf16x4*)out)[i] = o;
}

__global__ __launch_bounds__(256)
void zero_flags(int* __restrict__ flags, int n)
{
    int i = blockIdx.x * 256 + threadIdx.x;
    if (i < n) flags[i] = 0;
}

// ---------------------------------------------------------------------------
extern "C" void kernel_launch(void* const* d_in, const int* in_sizes, int n_in,
                              void* d_out, int out_size, void* d_ws, size_t ws_size,
                              hipStream_t stream)
{
    const int*   token_ids  = (const int*)  d_in[0];
    const float* embed      = (const float*)d_in[1];
    const float* W_in       = (const float*)d_in[2];
    const float* W_out      = (const float*)d_in[3];
    const float* layer_beta = (const float*)d_in[4];
    const float* layer_vth  = (const float*)d_in[5];
    const float* out_norm_w = (const float*)d_in[6];
    const float* out_beta   = (const float*)d_in[7];
    const float* out_vth    = (const float*)d_in[8];
    const float* out_alpha  = (const float*)d_in[9];
    const float* decode_w   = (const float*)d_in[10];
    const float* decode_b   = (const float*)d_in[11];
    const float* li_norm_w  = (const float*)d_in[12];
    float* out = (float*)d_out;

    size_t off = 0;
    auto alloc = [&](size_t bytes) -> void* {
        void* p = (char*)d_ws + off;
        off += (bytes + 255) & ~(size_t)255;
        return p;
    };
    float*  x_f32   = (float*) alloc((size_t)Tc * Bc * Dc * 4);   // also h after rmsnorm
    __bf16* x_bf    = (__bf16*)alloc((size_t)Tc * Bc * Dc * 2);
    __bf16* u_bf    = (__bf16*)alloc((size_t)Tc * Bc * Dc * 2);
    __bf16* spk     = (__bf16*)alloc((size_t)Tc * Bc * Dc * 2);
    __bf16* wT_in   = (__bf16*)alloc((size_t)NLc * Dc * Dc * 2);
    __bf16* wT_out  = (__bf16*)alloc((size_t)NLc * Dc * Dc * 2);
    __bf16* emb_bf  = (__bf16*)alloc((size_t)Vc * Dc * 2);
    __bf16* decw_bf = (__bf16*)alloc((size_t)Dc * Dc * 2);
    __bf16* xtok    = (__bf16*)alloc((size_t)Bc * Sc * Dc * 2);
    __bf16* u_tok   = (__bf16*)alloc((size_t)Bc * Sc * Dc * 2);
    __bf16* decoded = (__bf16*)alloc((size_t)Bc * Sc * Dc * 2);
    float*  h2      = (float*) alloc((size_t)Bc * Sc * Dc * 4);
    __bf16* h2n     = (__bf16*)alloc((size_t)Bc * Sc * Dc * 2);
    int*    flags   = (int*)   alloc((size_t)NLc * NPANEL * 4);

    zero_flags<<<(NLc * NPANEL + 255) / 256, 256, 0, stream>>>(flags, NLc * NPANEL);

    // weight prep
    transpose_cast<<<dim3(32, 32, NLc), dim3(32, 8), 0, stream>>>(W_in,  wT_in);
    transpose_cast<<<dim3(32, 32, NLc), dim3(32, 8), 0, stream>>>(W_out, wT_out);
    cast_bf16_k<<<(Vc * Dc / 4 + 255) / 256, 256, 0, stream>>>(embed, emb_bf, Vc * Dc / 4);
    cast_bf16_k<<<(Dc * Dc / 4 + 255) / 256, 256, 0, stream>>>(decode_w, decw_bf, Dc * Dc / 4);

    // encode
    encode<<<dim3(Tc, Bc), 256, 0, stream>>>(token_ids, embed, x_f32, x_bf, xtok);

    // layer 0 (token-level u GEMM: 32x less work)
    gemm_bt<3><<<dim3(Dc / 128, (Bc * Sc) / 128), 256, 0, stream>>>(
        xtok, wT_in, Bc * Sc, Dc, Dc, nullptr, nullptr, u_tok, nullptr, nullptr);
    layer_scan<1><<<dim3(Dc / 256, Bc, NSEG), 256, 0, stream>>>(
        u_tok, layer_beta, layer_vth, spk, flags);
    gemm_bt<1><<<dim3(Dc / 128, (Tc * Bc) / 128), 256, 0, stream>>>(
        spk, wT_out, Tc * Bc, Dc, Dc, nullptr, x_f32, x_bf, nullptr, flags);

    // layers 1..3
    for (int l = 1; l < NLc; ++l) {
        gemm_bt<3><<<dim3(Dc / 128, (Tc * Bc) / 128), 256, 0, stream>>>(
            x_bf, wT_in + (size_t)l * Dc * Dc, Tc * Bc, Dc, Dc,
            nullptr, nullptr, u_bf, nullptr, nullptr);
        layer_scan<0><<<dim3(Dc / 256, Bc, NSEG), 256, 0, stream>>>(
            u_bf, layer_beta + (size_t)l * Dc, layer_vth + (size_t)l * Dc,
            spk, flags + (size_t)l * NPANEL);
        gemm_bt<1><<<dim3(Dc / 128, (Tc * Bc) / 128), 256, 0, stream>>>(
            spk, wT_out + (size_t)l * Dc * Dc, Tc * Bc, Dc, Dc,
            nullptr, x_f32, x_bf, nullptr, flags + (size_t)l * NPANEL);
    }

    // decode head
    rmsnorm_rows<0><<<Tc * Bc, 256, 0, stream>>>(x_f32, out_norm_w, x_f32, nullptr);
    out_scan<<<dim3(Dc / 256, Bc, NSEG), 256, 0, stream>>>(
        x_f32, out_alpha, out_beta, out_vth, decoded);
    gemm_bt<2><<<dim3(Dc / 128, (Bc * Sc) / 128), 256, 0, stream>>>(
        decoded, decw_bf, Bc * Sc, Dc, Dc, h2, nullptr, nullptr, decode_b, nullptr);
    rmsnorm_rows<1><<<Bc * Sc, 256, 0, stream>>>(h2, li_norm_w, nullptr, h2n);
    gemm_bt<0><<<dim3(Vc / 128, (Bc * Sc) / 128), 256, 0, stream>>>(
        h2n, emb_bf, Bc * Sc, Vc, Dc, out, nullptr, nullptr, nullptr, nullptr);
}

// Round 3
// 300.139 us; speedup vs baseline: 2.6318x; 1.5218x over previous
//
#include <hip/hip_runtime.h>

typedef __bf16 bf16x8 __attribute__((ext_vector_type(8)));
typedef __bf16 bf16x4 __attribute__((ext_vector_type(4)));
typedef float  f32x4  __attribute__((ext_vector_type(4)));

constexpr int Bc = 2, Sc = 256, Kc = 32, Tc = 8192, Dc = 1024, Vc = 6144, NLc = 4;
constexpr int SEG = 256, NSEG = Tc / SEG;
constexpr int NPANEL = (Tc * Bc) / 128;   // 128 panels, each = 64 frames x both batches
constexpr int UTS = NLc * Dc;             // u_tok_all row stride (4096)

__device__ __forceinline__ void gload16(const void* g, void* l) {
    __builtin_amdgcn_global_load_lds(
        (const __attribute__((address_space(1))) unsigned int*)g,
        (__attribute__((address_space(3))) unsigned int*)l,
        16, 0, 0);
}

// bijective XCD-aware block swizzle (m204 variant)
__device__ __forceinline__ int xcd_swz(int lin, int nwg) {
    int q = nwg >> 3, r = nwg & 7;
    int x = lin & 7, o = lin >> 3;
    int base = (x < r) ? x * (q + 1) : r * (q + 1) + (x - r) * q;
    return base + o;
}

// OR of n flag arrays (stride NPANEL) at panel p — uniform scalar loads
__device__ __forceinline__ bool gate_or(const int* f, int n, int p) {
    bool g = false;
    for (int j = 0; j < n; ++j) g = g || (f[j * NPANEL + p] != 0);
    return g;
}

// ---------------------------------------------------------------------------
// GEMM: C[M][N] = A[M][K] (bf16 rm) x BT[N][K] (bf16 rm), 128x128 tile, BK=64,
// 4 waves (2x2), 4x4 mfma 16x16x32, swizzled LDS via pre-swizzled global src.
// EPI 0: Cout(f32)=acc                    EPI 2: Cout=acc+bias[col]
// EPI 3: outb=bf16(acc)
// EPI 4: [du]  exit if panel clean (OR prevf); outb=bf16(acc)
// EPI 5: [spk] exit if !exitf[panel]; dxio = bf16((prevdirty?dxio:0)+acc)
// ---------------------------------------------------------------------------
template<int EPI>
__global__ __launch_bounds__(256)
void gemm_bt(const __bf16* __restrict__ A, const __bf16* __restrict__ BT,
             int M, int N, int Kd,
             float* __restrict__ Cout, __bf16* __restrict__ dxio,
             __bf16* __restrict__ outb, const float* __restrict__ bias,
             const int* __restrict__ exitf, const int* __restrict__ prevf,
             int nprev)
{
    __shared__ char lds[32768];
    char* As = lds;
    char* Bs = lds + 16384;
    const int tid  = threadIdx.x;
    const int lane = tid & 63;
    const int wid  = tid >> 6;
    const int wm   = wid & 1, wn = wid >> 1;

    const int nwg = gridDim.x * gridDim.y;
    const int lin = blockIdx.y * gridDim.x + blockIdx.x;
    const int swz = xcd_swz(lin, nwg);
    const int bn  = (swz % gridDim.x) * 128;
    const int bm  = (swz / gridDim.x) * 128;

    bool prevdirty = false;
    if (EPI == 4 || EPI == 5) prevdirty = gate_or(prevf, nprev, bm >> 7);
    if (EPI == 4 && !prevdirty) return;
    if (EPI == 5 && exitf[bm >> 7] == 0) return;

    f32x4 acc[4][4] = {};

    for (int kt = 0; kt < Kd; kt += 64) {
#pragma unroll
        for (int i = 0; i < 4; ++i) {
            int chunk = i * 256 + tid;            // 1024 chunks of 16B
            int row = chunk >> 3, kc = chunk & 7;
            int kcs = kc ^ (row & 7);             // pre-swizzled global source
            gload16(A  + (size_t)(bm + row) * Kd + kt + kcs * 8, As + chunk * 16);
            gload16(BT + (size_t)(bn + row) * Kd + kt + kcs * 8, Bs + chunk * 16);
        }
        __syncthreads();
#pragma unroll
        for (int kk = 0; kk < 2; ++kk) {
            const int ko = kk * 64 + ((lane >> 4) << 4);
            bf16x8 af[4], bfr[4];
#pragma unroll
            for (int mi = 0; mi < 4; ++mi) {
                int row = wm * 64 + mi * 16 + (lane & 15);
                af[mi] = *(const bf16x8*)(As + row * 128 + (ko ^ ((row & 7) << 4)));
            }
#pragma unroll
            for (int ni = 0; ni < 4; ++ni) {
                int row = wn * 64 + ni * 16 + (lane & 15);
                bfr[ni] = *(const bf16x8*)(Bs + row * 128 + (ko ^ ((row & 7) << 4)));
            }
#pragma unroll
            for (int mi = 0; mi < 4; ++mi)
#pragma unroll
                for (int ni = 0; ni < 4; ++ni)
                    acc[mi][ni] = __builtin_amdgcn_mfma_f32_16x16x32_bf16(
                        af[mi], bfr[ni], acc[mi][ni], 0, 0, 0);
        }
        __syncthreads();
    }

    const int cc = lane & 15, cr = (lane >> 4) * 4;
#pragma unroll
    for (int mi = 0; mi < 4; ++mi) {
#pragma unroll
        for (int ni = 0; ni < 4; ++ni) {
            int gcol = bn + wn * 64 + ni * 16 + cc;
#pragma unroll
            for (int r = 0; r < 4; ++r) {
                int grow = bm + wm * 64 + mi * 16 + cr + r;
                size_t idx = (size_t)grow * N + gcol;
                float v = acc[mi][ni][r];
                if (EPI == 0) {
                    Cout[idx] = v;
                } else if (EPI == 2) {
                    Cout[idx] = v + bias[gcol];
                } else if (EPI == 3 || EPI == 4) {
                    outb[idx] = (__bf16)v;
                } else if (EPI == 5) {
                    float base = prevdirty ? (float)dxio[idx] : 0.0f;
                    dxio[idx] = (__bf16)(base + v);
                }
            }
        }
    }
}

// ---------------------------------------------------------------------------
// PLIF scan per chain (b,e): V = beta*V + u[t]; u[t] = u_tok[s] (+ du[t] if
// panel dirty). Segments of 256 frames, 64-frame warm-up (beta<=0.5 -> exact).
// Writes spk (always) and per-panel spike flags.
// ---------------------------------------------------------------------------
__global__ __launch_bounds__(256)
void layer_scan(const __bf16* __restrict__ utok, const __bf16* __restrict__ du,
                const float* __restrict__ beta, const float* __restrict__ vth,
                __bf16* __restrict__ spk, int* __restrict__ flags_l,
                const int* __restrict__ prevf, int nprev)
{
    const int e = blockIdx.x * 256 + threadIdx.x;
    const int b = blockIdx.y;
    const int seg = blockIdx.z;
    const int lane = threadIdx.x & 63;
    const float bet = beta[e];
    const float vt  = vth[e];
    const __bf16 vtb = (__bf16)vt;
    const __bf16 zb  = (__bf16)0.0f;
    float V = 0.0f;
    const int t0 = seg * SEG;
    if (seg != 0) {
        const int c = (t0 >> 6) - 1;
        const bool g = gate_or(prevf, nprev, c);
        for (int t = t0 - 64; t < t0; ++t) {
            float u = (float)utok[((size_t)(t >> 5) * Bc + b) * UTS + e];
            if (g) u += (float)du[((size_t)t * Bc + b) * Dc + e];
            V = fmaf(bet, V, u);
        }
    }
    unsigned anyv = 0;
    for (int j = 0; j < SEG / 64; ++j) {
        const int c = (t0 >> 6) + j;
        const bool g = gate_or(prevf, nprev, c);
        for (int k = 0; k < 64; ++k) {
            int t = t0 + j * 64 + k;
            float u = (float)utok[((size_t)(t >> 5) * Bc + b) * UTS + e];
            if (g) u += (float)du[((size_t)t * Bc + b) * Dc + e];
            V = fmaf(bet, V, u);
            bool sp = (V >= vt);
            if (sp) anyv |= 1u << j;
            spk[((size_t)t * Bc + b) * Dc + e] = sp ? vtb : zb;
        }
    }
#pragma unroll
    for (int j = 0; j < SEG / 64; ++j) {
        if (__any(anyv & (1u << j)) && lane == 0)
            atomicOr(&flags_l[(t0 >> 6) + j], 1);
    }
}

// ---------------------------------------------------------------------------
// Output PLIF scan fused with K-frame mean. h[t] = htok[s] (clean) or
// hframe[t] (dirty panel). decoded is b-major: [b][s][d].
// ---------------------------------------------------------------------------
__global__ __launch_bounds__(256)
void out_scan(const float* __restrict__ htok, const float* __restrict__ hframe,
              const float* __restrict__ alpha_p, const float* __restrict__ beta,
              const float* __restrict__ vth, const int* __restrict__ flags,
              __bf16* __restrict__ decoded)
{
    const int d = blockIdx.x * 256 + threadIdx.x;
    const int b = blockIdx.y;
    const int seg = blockIdx.z;
    const float al  = alpha_p[0];
    const float bet = beta[d];
    const float vt  = vth[d];
    float V = 0.0f;
    const int t0 = seg * SEG;
    if (seg != 0) {
        const int c = (t0 >> 6) - 1;
        const bool g = gate_or(flags, NLc, c);
        for (int t = t0 - 64; t < t0; ++t) {
            float h = g ? hframe[((size_t)t * Bc + b) * Dc + d]
                        : htok[((size_t)(t >> 5) * Bc + b) * Dc + d];
            V = fmaf(bet, V, al * h);
        }
    }
    float sum = 0.0f;
    for (int j = 0; j < SEG / 64; ++j) {
        const int c = (t0 >> 6) + j;
        const bool g = gate_or(flags, NLc, c);
        for (int k = 0; k < 64; ++k) {
            int t = t0 + j * 64 + k;
            float h = g ? hframe[((size_t)t * Bc + b) * Dc + d]
                        : htok[((size_t)(t >> 5) * Bc + b) * Dc + d];
            V = fmaf(bet, V, al * h);
            sum += (V >= vt) ? vt : 0.0f;
            if ((t & 31) == 31) {
                int s = t >> 5;
                decoded[((size_t)b * Sc + s) * Dc + d] = (__bf16)(sum * (1.0f / 32.0f));
                sum = 0.0f;
            }
        }
    }
}

// encode: per token row (s,b): gather embed f32, write xtok bf16 and
// htok = rmsnorm(emb)*out_norm_w (valid for clean rows).
__global__ __launch_bounds__(256)
void encode_tok(const int* __restrict__ tok, const float* __restrict__ embed,
                const float* __restrict__ w, __bf16* __restrict__ xtok,
                float* __restrict__ htok)
{
    const int s = blockIdx.x, b = blockIdx.y, tid = threadIdx.x;
    const int id = tok[b * Sc + s];
    const f32x4 v = ((const f32x4*)(embed + (size_t)id * Dc))[tid];
    float ss = v[0]*v[0] + v[1]*v[1] + v[2]*v[2] + v[3]*v[3];
#pragma unroll
    for (int off = 32; off >= 1; off >>= 1) ss += __shfl_down(ss, off);
    __shared__ float red[4];
    if ((tid & 63) == 0) red[tid >> 6] = ss;
    __syncthreads();
    float tot = red[0] + red[1] + red[2] + red[3];
    float sc = rsqrtf(tot * (1.0f / Dc) + 1e-6f);
    const f32x4 wv = ((const f32x4*)w)[tid];
    size_t r = (size_t)s * Bc + b;
    bf16x4 o; o[0]=(__bf16)v[0]; o[1]=(__bf16)v[1]; o[2]=(__bf16)v[2]; o[3]=(__bf16)v[3];
    ((bf16x4*)(xtok + r * Dc))[tid] = o;
    f32x4 h = {v[0]*sc*wv[0], v[1]*sc*wv[1], v[2]*sc*wv[2], v[3]*sc*wv[3]};
    ((f32x4*)(htok + r * Dc))[tid] = h;
}

// hframe for dirty panels: x = emb + dx, per-row rmsnorm * out_norm_w.
// grid (NPANEL, 8): block handles 16 rows of its panel; exits if clean.
__global__ __launch_bounds__(256)
void hframe_dirty(const int* __restrict__ tok, const float* __restrict__ embed,
                  const __bf16* __restrict__ dx, const float* __restrict__ w,
                  const int* __restrict__ flags, float* __restrict__ hf)
{
    const int panel = blockIdx.x;
    if (!gate_or(flags, NLc, panel)) return;
    const int tid = threadIdx.x;
    const f32x4 wv = ((const f32x4*)w)[tid];
    __shared__ float red[4];
    for (int i = 0; i < 16; ++i) {
        int r = panel * 128 + blockIdx.y * 16 + i;
        int t = r >> 1, b = r & 1, s = t >> 5;
        int id = tok[b * Sc + s];
        f32x4 v = ((const f32x4*)(embed + (size_t)id * Dc))[tid];
        bf16x4 dv = ((const bf16x4*)(dx + (size_t)r * Dc))[tid];
        v[0] += (float)dv[0]; v[1] += (float)dv[1];
        v[2] += (float)dv[2]; v[3] += (float)dv[3];
        float ss = v[0]*v[0] + v[1]*v[1] + v[2]*v[2] + v[3]*v[3];
#pragma unroll
        for (int off = 32; off >= 1; off >>= 1) ss += __shfl_down(ss, off);
        if ((tid & 63) == 0) red[tid >> 6] = ss;
        __syncthreads();
        float tot = red[0] + red[1] + red[2] + red[3];
        __syncthreads();
        float sc = rsqrtf(tot * (1.0f / Dc) + 1e-6f);
        f32x4 h = {v[0]*sc*wv[0], v[1]*sc*wv[1], v[2]*sc*wv[2], v[3]*sc*wv[3]};
        ((f32x4*)(hf + (size_t)r * Dc))[tid] = h;
    }
}

// RMSNorm over D=1024 per row -> bf16
__global__ __launch_bounds__(256)
void rmsnorm_rows(const float* __restrict__ in, const float* __restrict__ w,
                  __bf16* __restrict__ outb)
{
    const int r = blockIdx.x;
    const int tid = threadIdx.x;
    const f32x4 v = ((const f32x4*)(in + (size_t)r * Dc))[tid];
    float ss = v[0]*v[0] + v[1]*v[1] + v[2]*v[2] + v[3]*v[3];
#pragma unroll
    for (int off = 32; off >= 1; off >>= 1) ss += __shfl_down(ss, off);
    __shared__ float red[4];
    if ((tid & 63) == 0) red[tid >> 6] = ss;
    __syncthreads();
    float tot = red[0] + red[1] + red[2] + red[3];
    float sc = rsqrtf(tot * (1.0f / Dc) + 1e-6f);
    const f32x4 wv = ((const f32x4*)w)[tid];
    bf16x4 o;
    o[0]=(__bf16)(v[0]*sc*wv[0]); o[1]=(__bf16)(v[1]*sc*wv[1]);
    o[2]=(__bf16)(v[2]*sc*wv[2]); o[3]=(__bf16)(v[3]*sc*wv[3]);
    ((bf16x4*)(outb + (size_t)r * Dc))[tid] = o;
}

// W (D x D, f32) -> W^T (D x D, bf16); blockIdx.z = matrix id
__global__ __launch_bounds__(256)
void transpose_cast(const float* __restrict__ Ws, __bf16* __restrict__ Wd)
{
    __shared__ float tile[32][33];
    const float* Wm = Ws + (size_t)blockIdx.z * Dc * Dc;
    __bf16*      Wo = Wd + (size_t)blockIdx.z * Dc * Dc;
    const int tx = threadIdx.x, ty = threadIdx.y;
    const int d0 = blockIdx.x * 32, e0 = blockIdx.y * 32;
#pragma unroll
    for (int i = 0; i < 4; ++i)
        tile[ty + i*8][tx] = Wm[(size_t)(d0 + ty + i*8) * Dc + e0 + tx];
    __syncthreads();
#pragma unroll
    for (int i = 0; i < 4; ++i)
        Wo[(size_t)(e0 + ty + i*8) * Dc + d0 + tx] = (__bf16)tile[tx][ty + i*8];
}

__global__ __launch_bounds__(256)
void cast_bf16_k(const float* __restrict__ in, __bf16* __restrict__ out, int n4)
{
    int i = blockIdx.x * 256 + threadIdx.x;
    if (i >= n4) return;
    f32x4 v = ((const f32x4*)in)[i];
    bf16x4 o; o[0]=(__bf16)v[0]; o[1]=(__bf16)v[1]; o[2]=(__bf16)v[2]; o[3]=(__bf16)v[3];
    ((bf16x4*)out)[i] = o;
}

__global__ __launch_bounds__(256)
void zero_flags(int* __restrict__ flags, int n)
{
    int i = blockIdx.x * 256 + threadIdx.x;
    if (i < n) flags[i] = 0;
}

// ---------------------------------------------------------------------------
extern "C" void kernel_launch(void* const* d_in, const int* in_sizes, int n_in,
                              void* d_out, int out_size, void* d_ws, size_t ws_size,
                              hipStream_t stream)
{
    const int*   token_ids  = (const int*)  d_in[0];
    const float* embed      = (const float*)d_in[1];
    const float* W_in       = (const float*)d_in[2];
    const float* W_out      = (const float*)d_in[3];
    const float* layer_beta = (const float*)d_in[4];
    const float* layer_vth  = (const float*)d_in[5];
    const float* out_norm_w = (const float*)d_in[6];
    const float* out_beta   = (const float*)d_in[7];
    const float* out_vth    = (const float*)d_in[8];
    const float* out_alpha  = (const float*)d_in[9];
    const float* decode_w   = (const float*)d_in[10];
    const float* decode_b   = (const float*)d_in[11];
    const float* li_norm_w  = (const float*)d_in[12];
    float* out = (float*)d_out;

    size_t off = 0;
    auto alloc = [&](size_t bytes) -> void* {
        void* p = (char*)d_ws + off;
        off += (bytes + 255) & ~(size_t)255;
        return p;
    };
    float*  h_frame  = (float*) alloc((size_t)Tc * Bc * Dc * 4);   // dirty rows only
    __bf16* du       = (__bf16*)alloc((size_t)Tc * Bc * Dc * 2);   // dirty panels only
    __bf16* dx       = (__bf16*)alloc((size_t)Tc * Bc * Dc * 2);   // dirty panels only
    __bf16* spk      = (__bf16*)alloc((size_t)Tc * Bc * Dc * 2);
    __bf16* u_tokall = (__bf16*)alloc((size_t)Bc * Sc * UTS * 2);  // [512][4096]
    float*  h_tok    = (float*) alloc((size_t)Bc * Sc * Dc * 4);
    __bf16* xtok     = (__bf16*)alloc((size_t)Bc * Sc * Dc * 2);
    __bf16* wT_in    = (__bf16*)alloc((size_t)NLc * Dc * Dc * 2);
    __bf16* wT_out   = (__bf16*)alloc((size_t)NLc * Dc * Dc * 2);
    __bf16* emb_bf   = (__bf16*)alloc((size_t)Vc * Dc * 2);
    __bf16* decw_bf  = (__bf16*)alloc((size_t)Dc * Dc * 2);
    __bf16* decoded  = (__bf16*)alloc((size_t)Bc * Sc * Dc * 2);
    float*  h2       = (float*) alloc((size_t)Bc * Sc * Dc * 4);
    __bf16* h2n      = (__bf16*)alloc((size_t)Bc * Sc * Dc * 2);
    int*    flags    = (int*)   alloc((size_t)NLc * NPANEL * 4);   // per-layer spike flags

    zero_flags<<<(NLc * NPANEL + 255) / 256, 256, 0, stream>>>(flags, NLc * NPANEL);

    // weight prep
    transpose_cast<<<dim3(32, 32, NLc), dim3(32, 8), 0, stream>>>(W_in,  wT_in);
    transpose_cast<<<dim3(32, 32, NLc), dim3(32, 8), 0, stream>>>(W_out, wT_out);
    cast_bf16_k<<<(Vc * Dc / 4 + 255) / 256, 256, 0, stream>>>(embed, emb_bf, Vc * Dc / 4);
    cast_bf16_k<<<(Dc * Dc / 4 + 255) / 256, 256, 0, stream>>>(decode_w, decw_bf, Dc * Dc / 4);

    // encode (token level) + all-layer token-level u in ONE GEMM:
    // u_tokall[512][4*1024] = xtok[512][1024] x concat(W_in^T)[4096][1024]
    encode_tok<<<dim3(Sc, Bc), 256, 0, stream>>>(token_ids, embed, out_norm_w,
                                                 xtok, h_tok);
    gemm_bt<3><<<dim3(UTS / 128, (Bc * Sc) / 128), 256, 0, stream>>>(
        xtok, wT_in, Bc * Sc, UTS, Dc, nullptr, nullptr, u_tokall, nullptr,
        nullptr, nullptr, 0);

    // SNN layers: frame-level work only on dirty/spiking panels
    for (int l = 0; l < NLc; ++l) {
        if (l > 0) {   // du = dx @ W_in[l], only for panels dirtied by layers < l
            gemm_bt<4><<<dim3(Dc / 128, (Tc * Bc) / 128), 256, 0, stream>>>(
                dx, wT_in + (size_t)l * Dc * Dc, Tc * Bc, Dc, Dc,
                nullptr, nullptr, du, nullptr, nullptr, flags, l);
        }
        layer_scan<<<dim3(Dc / 256, Bc, NSEG), 256, 0, stream>>>(
            u_tokall + (size_t)l * Dc, du, layer_beta + (size_t)l * Dc,
            layer_vth + (size_t)l * Dc, spk, flags + (size_t)l * NPANEL,
            flags, l);
        // dx += spk @ W_out[l], only for panels that spiked this layer
        gemm_bt<5><<<dim3(Dc / 128, (Tc * Bc) / 128), 256, 0, stream>>>(
            spk, wT_out + (size_t)l * Dc * Dc, Tc * Bc, Dc, Dc,
            nullptr, dx, nullptr, nullptr, flags + (size_t)l * NPANEL, flags, l);
    }

    // decode head
    hframe_dirty<<<dim3(NPANEL, 8), 256, 0, stream>>>(
        token_ids, embed, dx, out_norm_w, flags, h_frame);
    out_scan<<<dim3(Dc / 256, Bc, NSEG), 256, 0, stream>>>(
        h_tok, h_frame, out_alpha, out_beta, out_vth, flags, decoded);
    gemm_bt<2><<<dim3(Dc / 128, (Bc * Sc) / 128), 256, 0, stream>>>(
        decoded, decw_bf, Bc * Sc, Dc, Dc, h2, nullptr, nullptr, decode_b,
        nullptr, nullptr, 0);
    rmsnorm_rows<<<Bc * Sc, 256, 0, stream>>>(h2, li_norm_w, h2n);
    gemm_bt<0><<<dim3(Vc / 128, (Bc * Sc) / 128), 256, 0, stream>>>(
        h2n, emb_bf, Bc * Sc, Vc, Dc, out, nullptr, nullptr, nullptr,
        nullptr, nullptr, 0);
}

// Round 4
// 140.979 us; speedup vs baseline: 5.6030x; 2.1290x over previous
//
#include <hip/hip_runtime.h>

typedef __bf16 bf16x8 __attribute__((ext_vector_type(8)));
typedef __bf16 bf16x4 __attribute__((ext_vector_type(4)));
typedef float  f32x4  __attribute__((ext_vector_type(4)));

constexpr int Bc = 2, Sc = 256, Kc = 32, Tc = 8192, Dc = 1024, Vc = 6144, NLc = 4;
constexpr int SEG = 256, NSEG = Tc / SEG;
constexpr int NPANEL = (Tc * Bc) / 128;   // 128 panels, each = 64 frames x both batches
constexpr int UTS = NLc * Dc;             // u_tok_all row stride (4096)

__device__ __forceinline__ void gload16(const void* g, void* l) {
    __builtin_amdgcn_global_load_lds(
        (const __attribute__((address_space(1))) unsigned int*)g,
        (__attribute__((address_space(3))) unsigned int*)l,
        16, 0, 0);
}

// bijective XCD-aware block swizzle (m204 variant)
__device__ __forceinline__ int xcd_swz(int lin, int nwg) {
    int q = nwg >> 3, r = nwg & 7;
    int x = lin & 7, o = lin >> 3;
    int base = (x < r) ? x * (q + 1) : r * (q + 1) + (x - r) * q;
    return base + o;
}

// OR of n flag arrays (stride NPANEL) at panel p — uniform scalar loads
__device__ __forceinline__ bool gate_or(const int* f, int n, int p) {
    bool g = false;
    for (int j = 0; j < n; ++j) g = g || (f[j * NPANEL + p] != 0);
    return g;
}

// ---------------------------------------------------------------------------
// GEMM: C[M][N] = A[M][K] (bf16 rm) x BT[N][K] (bf16 rm), 128x128 tile, BK=64,
// 4 waves (2x2), 4x4 mfma 16x16x32, swizzled LDS via pre-swizzled global src.
// EPI 0: Cout(f32)=acc                    EPI 2: Cout=acc+bias[col]
// EPI 3: outb=bf16(acc)
// EPI 4: [du]  exit if panel clean (OR prevf); outb=bf16(acc)
// EPI 5: [spk] exit if !exitf[panel]; dxio = bf16((prevdirty?dxio:0)+acc)
// ---------------------------------------------------------------------------
template<int EPI>
__global__ __launch_bounds__(256)
void gemm_bt(const __bf16* __restrict__ A, const __bf16* __restrict__ BT,
             int M, int N, int Kd,
             float* __restrict__ Cout, __bf16* __restrict__ dxio,
             __bf16* __restrict__ outb, const float* __restrict__ bias,
             const int* __restrict__ exitf, const int* __restrict__ prevf,
             int nprev)
{
    __shared__ char lds[32768];
    char* As = lds;
    char* Bs = lds + 16384;
    const int tid  = threadIdx.x;
    const int lane = tid & 63;
    const int wid  = tid >> 6;
    const int wm   = wid & 1, wn = wid >> 1;

    const int nwg = gridDim.x * gridDim.y;
    const int lin = blockIdx.y * gridDim.x + blockIdx.x;
    const int swz = xcd_swz(lin, nwg);
    const int bn  = (swz % gridDim.x) * 128;
    const int bm  = (swz / gridDim.x) * 128;

    bool prevdirty = false;
    if (EPI == 4 || EPI == 5) prevdirty = gate_or(prevf, nprev, bm >> 7);
    if (EPI == 4 && !prevdirty) return;
    if (EPI == 5 && exitf[bm >> 7] == 0) return;

    f32x4 acc[4][4] = {};

    for (int kt = 0; kt < Kd; kt += 64) {
#pragma unroll
        for (int i = 0; i < 4; ++i) {
            int chunk = i * 256 + tid;            // 1024 chunks of 16B
            int row = chunk >> 3, kc = chunk & 7;
            int kcs = kc ^ (row & 7);             // pre-swizzled global source
            gload16(A  + (size_t)(bm + row) * Kd + kt + kcs * 8, As + chunk * 16);
            gload16(BT + (size_t)(bn + row) * Kd + kt + kcs * 8, Bs + chunk * 16);
        }
        __syncthreads();
#pragma unroll
        for (int kk = 0; kk < 2; ++kk) {
            const int ko = kk * 64 + ((lane >> 4) << 4);
            bf16x8 af[4], bfr[4];
#pragma unroll
            for (int mi = 0; mi < 4; ++mi) {
                int row = wm * 64 + mi * 16 + (lane & 15);
                af[mi] = *(const bf16x8*)(As + row * 128 + (ko ^ ((row & 7) << 4)));
            }
#pragma unroll
            for (int ni = 0; ni < 4; ++ni) {
                int row = wn * 64 + ni * 16 + (lane & 15);
                bfr[ni] = *(const bf16x8*)(Bs + row * 128 + (ko ^ ((row & 7) << 4)));
            }
#pragma unroll
            for (int mi = 0; mi < 4; ++mi)
#pragma unroll
                for (int ni = 0; ni < 4; ++ni)
                    acc[mi][ni] = __builtin_amdgcn_mfma_f32_16x16x32_bf16(
                        af[mi], bfr[ni], acc[mi][ni], 0, 0, 0);
        }
        __syncthreads();
    }

    const int cc = lane & 15, cr = (lane >> 4) * 4;
#pragma unroll
    for (int mi = 0; mi < 4; ++mi) {
#pragma unroll
        for (int ni = 0; ni < 4; ++ni) {
            int gcol = bn + wn * 64 + ni * 16 + cc;
#pragma unroll
            for (int r = 0; r < 4; ++r) {
                int grow = bm + wm * 64 + mi * 16 + cr + r;
                size_t idx = (size_t)grow * N + gcol;
                float v = acc[mi][ni][r];
                if (EPI == 0) {
                    Cout[idx] = v;
                } else if (EPI == 2) {
                    Cout[idx] = v + bias[gcol];
                } else if (EPI == 3 || EPI == 4) {
                    outb[idx] = (__bf16)v;
                } else if (EPI == 5) {
                    float base = prevdirty ? (float)dxio[idx] : 0.0f;
                    dxio[idx] = (__bf16)(base + v);
                }
            }
        }
    }
}

// ---------------------------------------------------------------------------
// Flag-only PLIF scan: V = beta*V + u[t], u = u_tok[s] (+ du[t] on dirty
// chunks). NO spk stores — records per-64-frame-chunk spike flags only.
// Clean chunks hoist u once per token (constant over its 32 frames).
// ---------------------------------------------------------------------------
__global__ __launch_bounds__(256)
void scan_flags(const __bf16* __restrict__ utok, const __bf16* __restrict__ du,
                const float* __restrict__ beta, const float* __restrict__ vth,
                int* __restrict__ flags_l,
                const int* __restrict__ prevf, int nprev)
{
    const int e = blockIdx.x * 256 + threadIdx.x;
    const int b = blockIdx.y;
    const int seg = blockIdx.z;
    const int lane = threadIdx.x & 63;
    const float bet = beta[e];
    const float vt  = vth[e];
    float V = 0.0f;
    const int t0 = seg * SEG;
    const int c0 = t0 >> 6;
    if (seg != 0) {
        const bool g = gate_or(prevf, nprev, c0 - 1);
        if (!g) {
            for (int tk = (t0 >> 5) - 2; tk < (t0 >> 5); ++tk) {
                const float u = (float)utok[((size_t)tk * Bc + b) * UTS + e];
                for (int k = 0; k < 32; ++k) V = fmaf(bet, V, u);
            }
        } else {
            for (int t = t0 - 64; t < t0; ++t) {
                float u = (float)utok[((size_t)(t >> 5) * Bc + b) * UTS + e]
                        + (float)du[((size_t)t * Bc + b) * Dc + e];
                V = fmaf(bet, V, u);
            }
        }
    }
    unsigned anyv = 0;
    for (int j = 0; j < SEG / 64; ++j) {
        const int c = c0 + j;
        const bool g = gate_or(prevf, nprev, c);
        bool sp_any = false;
        if (!g) {
            for (int ti = 0; ti < 2; ++ti) {
                const int tk = (t0 >> 5) + 2 * j + ti;
                const float u = (float)utok[((size_t)tk * Bc + b) * UTS + e];
                for (int k = 0; k < 32; ++k) {
                    V = fmaf(bet, V, u);
                    sp_any = sp_any || (V >= vt);
                }
            }
        } else {
            for (int k = 0; k < 64; ++k) {
                const int t = t0 + j * 64 + k;
                float u = (float)utok[((size_t)(t >> 5) * Bc + b) * UTS + e]
                        + (float)du[((size_t)t * Bc + b) * Dc + e];
                V = fmaf(bet, V, u);
                sp_any = sp_any || (V >= vt);
            }
        }
        if (sp_any) anyv |= 1u << j;
    }
#pragma unroll
    for (int j = 0; j < SEG / 64; ++j) {
        if (__any(anyv & (1u << j)) && lane == 0)
            atomicOr(&flags_l[c0 + j], 1);
    }
}

// ---------------------------------------------------------------------------
// Gated spike writer: early-exits unless some chunk of this segment is
// flagged; otherwise recomputes the recurrence and writes spk for flagged
// chunks (full panels — the gated GEMM reads only those).
// ---------------------------------------------------------------------------
__global__ __launch_bounds__(256)
void spk_write(const __bf16* __restrict__ utok, const __bf16* __restrict__ du,
               const float* __restrict__ beta, const float* __restrict__ vth,
               __bf16* __restrict__ spk, const int* __restrict__ flags_l,
               const int* __restrict__ prevf, int nprev)
{
    const int seg = blockIdx.z;
    const int t0 = seg * SEG;
    const int c0 = t0 >> 6;
    bool anyf = false;
    for (int j = 0; j < SEG / 64; ++j) anyf = anyf || (flags_l[c0 + j] != 0);
    if (!anyf) return;

    const int e = blockIdx.x * 256 + threadIdx.x;
    const int b = blockIdx.y;
    const float bet = beta[e];
    const float vt  = vth[e];
    const __bf16 vtb = (__bf16)vt;
    const __bf16 zb  = (__bf16)0.0f;
    float V = 0.0f;
    if (seg != 0) {
        const bool g = gate_or(prevf, nprev, c0 - 1);
        if (!g) {
            for (int tk = (t0 >> 5) - 2; tk < (t0 >> 5); ++tk) {
                const float u = (float)utok[((size_t)tk * Bc + b) * UTS + e];
                for (int k = 0; k < 32; ++k) V = fmaf(bet, V, u);
            }
        } else {
            for (int t = t0 - 64; t < t0; ++t) {
                float u = (float)utok[((size_t)(t >> 5) * Bc + b) * UTS + e]
                        + (float)du[((size_t)t * Bc + b) * Dc + e];
                V = fmaf(bet, V, u);
            }
        }
    }
    for (int j = 0; j < SEG / 64; ++j) {
        const int c = c0 + j;
        const bool g  = gate_or(prevf, nprev, c);
        const bool wj = (flags_l[c] != 0);
        for (int k = 0; k < 64; ++k) {
            const int t = t0 + j * 64 + k;
            float u = (float)utok[((size_t)(t >> 5) * Bc + b) * UTS + e];
            if (g) u += (float)du[((size_t)t * Bc + b) * Dc + e];
            V = fmaf(bet, V, u);
            if (wj) spk[((size_t)t * Bc + b) * Dc + e] = (V >= vt) ? vtb : zb;
        }
    }
}

// ---------------------------------------------------------------------------
// Output PLIF scan fused with K-frame mean. Clean chunks: h = htok[s] hoisted
// per token; dirty chunks: per-frame hframe. decoded is [b][s][d] bf16.
// ---------------------------------------------------------------------------
__global__ __launch_bounds__(256)
void out_scan(const float* __restrict__ htok, const float* __restrict__ hframe,
              const float* __restrict__ alpha_p, const float* __restrict__ beta,
              const float* __restrict__ vth, const int* __restrict__ flags,
              __bf16* __restrict__ decoded)
{
    const int d = blockIdx.x * 256 + threadIdx.x;
    const int b = blockIdx.y;
    const int seg = blockIdx.z;
    const float al  = alpha_p[0];
    const float bet = beta[d];
    const float vt  = vth[d];
    float V = 0.0f;
    const int t0 = seg * SEG;
    const int c0 = t0 >> 6;
    if (seg != 0) {
        const bool g = gate_or(flags, NLc, c0 - 1);
        if (!g) {
            for (int tk = (t0 >> 5) - 2; tk < (t0 >> 5); ++tk) {
                const float ah = al * htok[((size_t)tk * Bc + b) * Dc + d];
                for (int k = 0; k < 32; ++k) V = fmaf(bet, V, ah);
            }
        } else {
            for (int t = t0 - 64; t < t0; ++t)
                V = fmaf(bet, V, al * hframe[((size_t)t * Bc + b) * Dc + d]);
        }
    }
    for (int j = 0; j < SEG / 64; ++j) {
        const int c = c0 + j;
        const bool g = gate_or(flags, NLc, c);
        if (!g) {
            for (int ti = 0; ti < 2; ++ti) {
                const int tk = (t0 >> 5) + 2 * j + ti;
                const float ah = al * htok[((size_t)tk * Bc + b) * Dc + d];
                float sum = 0.0f;
                for (int k = 0; k < 32; ++k) {
                    V = fmaf(bet, V, ah);
                    sum += (V >= vt) ? vt : 0.0f;
                }
                decoded[((size_t)b * Sc + tk) * Dc + d] = (__bf16)(sum * (1.0f / 32.0f));
            }
        } else {
            float sum = 0.0f;
            for (int k = 0; k < 64; ++k) {
                const int t = t0 + j * 64 + k;
                V = fmaf(bet, V, al * hframe[((size_t)t * Bc + b) * Dc + d]);
                sum += (V >= vt) ? vt : 0.0f;
                if ((t & 31) == 31) {
                    const int s = t >> 5;
                    decoded[((size_t)b * Sc + s) * Dc + d] = (__bf16)(sum * (1.0f / 32.0f));
                    sum = 0.0f;
                }
            }
        }
    }
}

// encode: per token row (s,b): gather embed f32, write xtok bf16 and
// htok = rmsnorm(emb)*out_norm_w. Block (0,0) also zeroes the flag array.
__global__ __launch_bounds__(256)
void encode_tok(const int* __restrict__ tok, const float* __restrict__ embed,
                const float* __restrict__ w, __bf16* __restrict__ xtok,
                float* __restrict__ htok, int* __restrict__ flags)
{
    const int s = blockIdx.x, b = blockIdx.y, tid = threadIdx.x;
    if (s == 0 && b == 0) {
        flags[tid] = 0;
        flags[tid + 256] = 0;
    }
    const int id = tok[b * Sc + s];
    const f32x4 v = ((const f32x4*)(embed + (size_t)id * Dc))[tid];
    float ss = v[0]*v[0] + v[1]*v[1] + v[2]*v[2] + v[3]*v[3];
#pragma unroll
    for (int off = 32; off >= 1; off >>= 1) ss += __shfl_down(ss, off);
    __shared__ float red[4];
    if ((tid & 63) == 0) red[tid >> 6] = ss;
    __syncthreads();
    float tot = red[0] + red[1] + red[2] + red[3];
    float sc = rsqrtf(tot * (1.0f / Dc) + 1e-6f);
    const f32x4 wv = ((const f32x4*)w)[tid];
    size_t r = (size_t)s * Bc + b;
    bf16x4 o; o[0]=(__bf16)v[0]; o[1]=(__bf16)v[1]; o[2]=(__bf16)v[2]; o[3]=(__bf16)v[3];
    ((bf16x4*)(xtok + r * Dc))[tid] = o;
    f32x4 h = {v[0]*sc*wv[0], v[1]*sc*wv[1], v[2]*sc*wv[2], v[3]*sc*wv[3]};
    ((f32x4*)(htok + r * Dc))[tid] = h;
}

// hframe for dirty panels: x = emb + dx, per-row rmsnorm * out_norm_w.
__global__ __launch_bounds__(256)
void hframe_dirty(const int* __restrict__ tok, const float* __restrict__ embed,
                  const __bf16* __restrict__ dx, const float* __restrict__ w,
                  const int* __restrict__ flags, float* __restrict__ hf)
{
    const int panel = blockIdx.x;
    if (!gate_or(flags, NLc, panel)) return;
    const int tid = threadIdx.x;
    const f32x4 wv = ((const f32x4*)w)[tid];
    __shared__ float red[4];
    for (int i = 0; i < 16; ++i) {
        int r = panel * 128 + blockIdx.y * 16 + i;
        int t = r >> 1, b = r & 1, s = t >> 5;
        int id = tok[b * Sc + s];
        f32x4 v = ((const f32x4*)(embed + (size_t)id * Dc))[tid];
        bf16x4 dv = ((const bf16x4*)(dx + (size_t)r * Dc))[tid];
        v[0] += (float)dv[0]; v[1] += (float)dv[1];
        v[2] += (float)dv[2]; v[3] += (float)dv[3];
        float ss = v[0]*v[0] + v[1]*v[1] + v[2]*v[2] + v[3]*v[3];
#pragma unroll
        for (int off = 32; off >= 1; off >>= 1) ss += __shfl_down(ss, off);
        if ((tid & 63) == 0) red[tid >> 6] = ss;
        __syncthreads();
        float tot = red[0] + red[1] + red[2] + red[3];
        __syncthreads();
        float sc = rsqrtf(tot * (1.0f / Dc) + 1e-6f);
        f32x4 h = {v[0]*sc*wv[0], v[1]*sc*wv[1], v[2]*sc*wv[2], v[3]*sc*wv[3]};
        ((f32x4*)(hf + (size_t)r * Dc))[tid] = h;
    }
}

// RMSNorm over D=1024 per row -> bf16
__global__ __launch_bounds__(256)
void rmsnorm_rows(const float* __restrict__ in, const float* __restrict__ w,
                  __bf16* __restrict__ outb)
{
    const int r = blockIdx.x;
    const int tid = threadIdx.x;
    const f32x4 v = ((const f32x4*)(in + (size_t)r * Dc))[tid];
    float ss = v[0]*v[0] + v[1]*v[1] + v[2]*v[2] + v[3]*v[3];
#pragma unroll
    for (int off = 32; off >= 1; off >>= 1) ss += __shfl_down(ss, off);
    __shared__ float red[4];
    if ((tid & 63) == 0) red[tid >> 6] = ss;
    __syncthreads();
    float tot = red[0] + red[1] + red[2] + red[3];
    float sc = rsqrtf(tot * (1.0f / Dc) + 1e-6f);
    const f32x4 wv = ((const f32x4*)w)[tid];
    bf16x4 o;
    o[0]=(__bf16)(v[0]*sc*wv[0]); o[1]=(__bf16)(v[1]*sc*wv[1]);
    o[2]=(__bf16)(v[2]*sc*wv[2]); o[3]=(__bf16)(v[3]*sc*wv[3]);
    ((bf16x4*)(outb + (size_t)r * Dc))[tid] = o;
}

// W (D x D, f32) -> W^T (D x D, bf16); blockIdx.z = matrix id
__global__ __launch_bounds__(256)
void transpose_cast(const float* __restrict__ Ws, __bf16* __restrict__ Wd)
{
    __shared__ float tile[32][33];
    const float* Wm = Ws + (size_t)blockIdx.z * Dc * Dc;
    __bf16*      Wo = Wd + (size_t)blockIdx.z * Dc * Dc;
    const int tx = threadIdx.x, ty = threadIdx.y;
    const int d0 = blockIdx.x * 32, e0 = blockIdx.y * 32;
#pragma unroll
    for (int i = 0; i < 4; ++i)
        tile[ty + i*8][tx] = Wm[(size_t)(d0 + ty + i*8) * Dc + e0 + tx];
    __syncthreads();
#pragma unroll
    for (int i = 0; i < 4; ++i)
        Wo[(size_t)(e0 + ty + i*8) * Dc + d0 + tx] = (__bf16)tile[tx][ty + i*8];
}

__global__ __launch_bounds__(256)
void cast_bf16_k(const float* __restrict__ in, __bf16* __restrict__ out, int n4)
{
    int i = blockIdx.x * 256 + threadIdx.x;
    if (i >= n4) return;
    f32x4 v = ((const f32x4*)in)[i];
    bf16x4 o; o[0]=(__bf16)v[0]; o[1]=(__bf16)v[1]; o[2]=(__bf16)v[2]; o[3]=(__bf16)v[3];
    ((bf16x4*)out)[i] = o;
}

// ---------------------------------------------------------------------------
extern "C" void kernel_launch(void* const* d_in, const int* in_sizes, int n_in,
                              void* d_out, int out_size, void* d_ws, size_t ws_size,
                              hipStream_t stream)
{
    const int*   token_ids  = (const int*)  d_in[0];
    const float* embed      = (const float*)d_in[1];
    const float* W_in       = (const float*)d_in[2];
    const float* W_out      = (const float*)d_in[3];
    const float* layer_beta = (const float*)d_in[4];
    const float* layer_vth  = (const float*)d_in[5];
    const float* out_norm_w = (const float*)d_in[6];
    const float* out_beta   = (const float*)d_in[7];
    const float* out_vth    = (const float*)d_in[8];
    const float* out_alpha  = (const float*)d_in[9];
    const float* decode_w   = (const float*)d_in[10];
    const float* decode_b   = (const float*)d_in[11];
    const float* li_norm_w  = (const float*)d_in[12];
    float* out = (float*)d_out;

    size_t off = 0;
    auto alloc = [&](size_t bytes) -> void* {
        void* p = (char*)d_ws + off;
        off += (bytes + 255) & ~(size_t)255;
        return p;
    };
    float*  h_frame  = (float*) alloc((size_t)Tc * Bc * Dc * 4);   // dirty rows only
    __bf16* du       = (__bf16*)alloc((size_t)Tc * Bc * Dc * 2);   // dirty panels only
    __bf16* dx       = (__bf16*)alloc((size_t)Tc * Bc * Dc * 2);   // dirty panels only
    __bf16* spk      = (__bf16*)alloc((size_t)Tc * Bc * Dc * 2);   // flagged panels only
    __bf16* u_tokall = (__bf16*)alloc((size_t)Bc * Sc * UTS * 2);  // [512][4096]
    float*  h_tok    = (float*) alloc((size_t)Bc * Sc * Dc * 4);
    __bf16* xtok     = (__bf16*)alloc((size_t)Bc * Sc * Dc * 2);
    __bf16* wT_in    = (__bf16*)alloc((size_t)NLc * Dc * Dc * 2);
    __bf16* wT_out   = (__bf16*)alloc((size_t)NLc * Dc * Dc * 2);
    __bf16* emb_bf   = (__bf16*)alloc((size_t)Vc * Dc * 2);
    __bf16* decw_bf  = (__bf16*)alloc((size_t)Dc * Dc * 2);
    __bf16* decoded  = (__bf16*)alloc((size_t)Bc * Sc * Dc * 2);
    float*  h2       = (float*) alloc((size_t)Bc * Sc * Dc * 4);
    __bf16* h2n      = (__bf16*)alloc((size_t)Bc * Sc * Dc * 2);
    int*    flags    = (int*)   alloc((size_t)NLc * NPANEL * 4);   // per-layer spike flags

    // weight prep
    transpose_cast<<<dim3(32, 32, NLc), dim3(32, 8), 0, stream>>>(W_in,  wT_in);
    transpose_cast<<<dim3(32, 32, NLc), dim3(32, 8), 0, stream>>>(W_out, wT_out);
    cast_bf16_k<<<(Vc * Dc / 4 + 255) / 256, 256, 0, stream>>>(embed, emb_bf, Vc * Dc / 4);
    cast_bf16_k<<<(Dc * Dc / 4 + 255) / 256, 256, 0, stream>>>(decode_w, decw_bf, Dc * Dc / 4);

    // encode (token level, zeroes flags) + all-layer token-level u in ONE GEMM
    encode_tok<<<dim3(Sc, Bc), 256, 0, stream>>>(token_ids, embed, out_norm_w,
                                                 xtok, h_tok, flags);
    gemm_bt<3><<<dim3(UTS / 128, (Bc * Sc) / 128), 256, 0, stream>>>(
        xtok, wT_in, Bc * Sc, UTS, Dc, nullptr, nullptr, u_tokall, nullptr,
        nullptr, nullptr, 0);

    // SNN layers: frame-level work only on dirty/spiking panels
    for (int l = 0; l < NLc; ++l) {
        if (l > 0) {   // du = dx @ W_in[l], only for panels dirtied by layers < l
            gemm_bt<4><<<dim3(Dc / 128, (Tc * Bc) / 128), 256, 0, stream>>>(
                dx, wT_in + (size_t)l * Dc * Dc, Tc * Bc, Dc, Dc,
                nullptr, nullptr, du, nullptr, nullptr, flags, l);
        }
        scan_flags<<<dim3(Dc / 256, Bc, NSEG), 256, 0, stream>>>(
            u_tokall + (size_t)l * Dc, du, layer_beta + (size_t)l * Dc,
            layer_vth + (size_t)l * Dc, flags + (size_t)l * NPANEL, flags, l);
        spk_write<<<dim3(Dc / 256, Bc, NSEG), 256, 0, stream>>>(
            u_tokall + (size_t)l * Dc, du, layer_beta + (size_t)l * Dc,
            layer_vth + (size_t)l * Dc, spk, flags + (size_t)l * NPANEL,
            flags, l);
        // dx += spk @ W_out[l], only for panels that spiked this layer
        gemm_bt<5><<<dim3(Dc / 128, (Tc * Bc) / 128), 256, 0, stream>>>(
            spk, wT_out + (size_t)l * Dc * Dc, Tc * Bc, Dc, Dc,
            nullptr, dx, nullptr, nullptr, flags + (size_t)l * NPANEL, flags, l);
    }

    // decode head
    hframe_dirty<<<dim3(NPANEL, 8), 256, 0, stream>>>(
        token_ids, embed, dx, out_norm_w, flags, h_frame);
    out_scan<<<dim3(Dc / 256, Bc, NSEG), 256, 0, stream>>>(
        h_tok, h_frame, out_alpha, out_beta, out_vth, flags, decoded);
    gemm_bt<2><<<dim3(Dc / 128, (Bc * Sc) / 128), 256, 0, stream>>>(
        decoded, decw_bf, Bc * Sc, Dc, Dc, h2, nullptr, nullptr, decode_b,
        nullptr, nullptr, 0);
    rmsnorm_rows<<<Bc * Sc, 256, 0, stream>>>(h2, li_norm_w, h2n);
    gemm_bt<0><<<dim3(Vc / 128, (Bc * Sc) / 128), 256, 0, stream>>>(
        h2n, emb_bf, Bc * Sc, Vc, Dc, out, nullptr, nullptr, nullptr,
        nullptr, nullptr, 0);
}

// Round 5
// 138.827 us; speedup vs baseline: 5.6899x; 1.0155x over previous
//
#include <hip/hip_runtime.h>

typedef __bf16 bf16x8 __attribute__((ext_vector_type(8)));
typedef __bf16 bf16x4 __attribute__((ext_vector_type(4)));
typedef float  f32x4  __attribute__((ext_vector_type(4)));

constexpr int Bc = 2, Sc = 256, Kc = 32, Tc = 8192, Dc = 1024, Vc = 6144, NLc = 4;
constexpr int SEG = 256, NSEG = Tc / SEG;
constexpr int NPANEL = (Tc * Bc) / 128;   // 128 panels (64 frames x both batches)
constexpr int UTS = NLc * Dc;             // u_tok_all row stride (4096)

__device__ __forceinline__ void gload16(const void* g, void* l) {
    __builtin_amdgcn_global_load_lds(
        (const __attribute__((address_space(1))) unsigned int*)g,
        (__attribute__((address_space(3))) unsigned int*)l,
        16, 0, 0);
}

// bijective XCD-aware block swizzle (m204 variant)
__device__ __forceinline__ int xcd_swz(int lin, int nwg) {
    int q = nwg >> 3, r = nwg & 7;
    int x = lin & 7, o = lin >> 3;
    int base = (x < r) ? x * (q + 1) : r * (q + 1) + (x - r) * q;
    return base + o;
}

// OR of n flag arrays (stride NPANEL) at panel p — uniform scalar loads
__device__ __forceinline__ bool gate_or(const int* f, int n, int p) {
    bool g = false;
    for (int j = 0; j < n; ++j) g = g || (f[j * NPANEL + p] != 0);
    return g;
}

// ---------------------------------------------------------------------------
// GEMM: C[M][N] = A[M][K] (bf16 rm) x BT[N][K] (bf16 rm), 128x128 tile, BK=64,
// 4 waves (2x2), 4x4 mfma 16x16x32, swizzled LDS via pre-swizzled global src.
// GATHER: A row r -> emb row tok[(r&1)*Sc + (r>>1)] (token-level u GEMM).
// EPI 0: Cout(f32)=acc                    EPI 2: Cout=acc+bias[col]
// EPI 3: outb=bf16(acc)
// EPI 4: [du]  exit if panel clean (OR prevf); outb=bf16(acc)
// EPI 5: [spk] exit if !exitf[panel]; dxio = bf16((prevdirty?dxio:0)+acc)
// ---------------------------------------------------------------------------
template<int EPI, int GATHER = 0>
__global__ __launch_bounds__(256)
void gemm_bt(const __bf16* __restrict__ A, const __bf16* __restrict__ BT,
             int M, int N, int Kd,
             float* __restrict__ Cout, __bf16* __restrict__ dxio,
             __bf16* __restrict__ outb, const float* __restrict__ bias,
             const int* __restrict__ exitf, const int* __restrict__ prevf,
             int nprev, const int* __restrict__ tok)
{
    __shared__ char lds[32768];
    char* As = lds;
    char* Bs = lds + 16384;
    const int tid  = threadIdx.x;
    const int lane = tid & 63;
    const int wid  = tid >> 6;
    const int wm   = wid & 1, wn = wid >> 1;

    const int nwg = gridDim.x * gridDim.y;
    const int lin = blockIdx.y * gridDim.x + blockIdx.x;
    const int swz = xcd_swz(lin, nwg);
    const int bn  = (swz % gridDim.x) * 128;
    const int bm  = (swz / gridDim.x) * 128;

    bool prevdirty = false;
    if (EPI == 4 || EPI == 5) prevdirty = gate_or(prevf, nprev, bm >> 7);
    if (EPI == 4 && !prevdirty) return;
    if (EPI == 5 && exitf[bm >> 7] == 0) return;

    // hoist staging source addresses out of the K-loop
    const __bf16* asrc[4];
    const __bf16* bsrc[4];
#pragma unroll
    for (int i = 0; i < 4; ++i) {
        int chunk = i * 256 + tid;            // 1024 chunks of 16B
        int row = chunk >> 3, kc = chunk & 7;
        int kcs = kc ^ (row & 7);             // pre-swizzled global source
        int gr = bm + row;
        const __bf16* abase;
        if (GATHER) {
            int id = tok[(gr & 1) * Sc + (gr >> 1)];
            abase = A + (size_t)id * Kd;
        } else {
            abase = A + (size_t)gr * Kd;
        }
        asrc[i] = abase + kcs * 8;
        bsrc[i] = BT + (size_t)(bn + row) * Kd + kcs * 8;
    }

    f32x4 acc[4][4] = {};

    for (int kt = 0; kt < Kd; kt += 64) {
#pragma unroll
        for (int i = 0; i < 4; ++i) {
            int chunk = i * 256 + tid;
            gload16(asrc[i] + kt, As + chunk * 16);
            gload16(bsrc[i] + kt, Bs + chunk * 16);
        }
        __syncthreads();
#pragma unroll
        for (int kk = 0; kk < 2; ++kk) {
            const int ko = kk * 64 + ((lane >> 4) << 4);
            bf16x8 af[4], bfr[4];
#pragma unroll
            for (int mi = 0; mi < 4; ++mi) {
                int row = wm * 64 + mi * 16 + (lane & 15);
                af[mi] = *(const bf16x8*)(As + row * 128 + (ko ^ ((row & 7) << 4)));
            }
#pragma unroll
            for (int ni = 0; ni < 4; ++ni) {
                int row = wn * 64 + ni * 16 + (lane & 15);
                bfr[ni] = *(const bf16x8*)(Bs + row * 128 + (ko ^ ((row & 7) << 4)));
            }
#pragma unroll
            for (int mi = 0; mi < 4; ++mi)
#pragma unroll
                for (int ni = 0; ni < 4; ++ni)
                    acc[mi][ni] = __builtin_amdgcn_mfma_f32_16x16x32_bf16(
                        af[mi], bfr[ni], acc[mi][ni], 0, 0, 0);
        }
        __syncthreads();
    }

    const int cc = lane & 15, cr = (lane >> 4) * 4;
#pragma unroll
    for (int mi = 0; mi < 4; ++mi) {
#pragma unroll
        for (int ni = 0; ni < 4; ++ni) {
            int gcol = bn + wn * 64 + ni * 16 + cc;
#pragma unroll
            for (int r = 0; r < 4; ++r) {
                int grow = bm + wm * 64 + mi * 16 + cr + r;
                size_t idx = (size_t)grow * N + gcol;
                float v = acc[mi][ni][r];
                if (EPI == 0) {
                    Cout[idx] = v;
                } else if (EPI == 2) {
                    Cout[idx] = v + bias[gcol];
                } else if (EPI == 3 || EPI == 4) {
                    outb[idx] = (__bf16)v;
                } else if (EPI == 5) {
                    float base = prevdirty ? (float)dxio[idx] : 0.0f;
                    dxio[idx] = (__bf16)(base + v);
                }
            }
        }
    }
}

// ---------------------------------------------------------------------------
// Fused PLIF scan: flags + gated spike write in ONE kernel.
// One block per segment (32 blocks x 1024 threads = all e); loops b in-thread.
// Clean chunks: exact closed form of the constant-u recurrence
//   V_32 = a32*V0 + u*S32  (a32=beta^32, S32=sum beta^i), monotone in k
//   -> spike-any = max(V_1, V_32) >= vt.
// Chunk flags reduced block-locally (LDS); spike-write phase (stepwise)
// runs only if some chunk of this segment flagged.
// ---------------------------------------------------------------------------
__global__ __launch_bounds__(1024)
void scanA(const __bf16* __restrict__ utok, const __bf16* __restrict__ du,
           const float* __restrict__ beta, const float* __restrict__ vth,
           __bf16* __restrict__ spk, int* __restrict__ flags_l,
           const int* __restrict__ prevf, int nprev)
{
    const int e   = threadIdx.x;
    const int seg = blockIdx.x;
    const int t0  = seg * SEG;
    const int c0  = t0 >> 6;
    const float bet = beta[e];
    const float vt  = vth[e];
    float a = bet, S = 1.0f;                 // -> a=beta^32, S=S32 (5 doublings)
#pragma unroll
    for (int i = 0; i < 5; ++i) { S = S * (1.0f + a); a = a * a; }

    __shared__ int fm;
    if (e == 0) fm = 0;
    __syncthreads();

    unsigned mask = 0;
    for (int b = 0; b < Bc; ++b) {
        float V = 0.0f;
        if (seg != 0) {
            const bool g = (nprev > 0) && gate_or(prevf, nprev, c0 - 1);
            if (!g) {
                const int tk0 = (t0 >> 5) - 2;
#pragma unroll
                for (int ti = 0; ti < 2; ++ti) {
                    float u = (float)utok[((size_t)(tk0 + ti) * Bc + b) * UTS + e];
                    V = fmaf(a, V, u * S);
                }
            } else {
                for (int t = t0 - 64; t < t0; ++t) {
                    float u = (float)utok[((size_t)(t >> 5) * Bc + b) * UTS + e]
                            + (float)du[((size_t)t * Bc + b) * Dc + e];
                    V = fmaf(bet, V, u);
                }
            }
        }
        for (int j = 0; j < SEG / 64; ++j) {
            const bool g = (nprev > 0) && gate_or(prevf, nprev, c0 + j);
            if (!g) {
                float mx = -1e30f;
#pragma unroll
                for (int ti = 0; ti < 2; ++ti) {
                    const int tk = (t0 >> 5) + 2 * j + ti;
                    float u  = (float)utok[((size_t)tk * Bc + b) * UTS + e];
                    float V1 = fmaf(bet, V, u);          // first step of window
                    V = fmaf(a, V, u * S);               // after 32 steps
                    mx = fmaxf(mx, fmaxf(V1, V));        // monotone => endpoints
                }
                if (mx >= vt) mask |= 1u << j;
            } else {
                bool any = false;
                for (int k = 0; k < 64; ++k) {
                    const int t = t0 + j * 64 + k;
                    float u = (float)utok[((size_t)(t >> 5) * Bc + b) * UTS + e]
                            + (float)du[((size_t)t * Bc + b) * Dc + e];
                    V = fmaf(bet, V, u);
                    any = any || (V >= vt);
                }
                if (any) mask |= 1u << j;
            }
        }
    }
    if (mask) atomicOr(&fm, (int)mask);
    __syncthreads();
    const int f = fm;
    if (e < SEG / 64) flags_l[c0 + e] = (f >> e) & 1;   // exclusive owner
    if (f == 0) return;

    // ---- spike write phase (rare): stepwise recompute, write flagged chunks
    const __bf16 vtb = (__bf16)vt;
    const __bf16 zb  = (__bf16)0.0f;
    for (int b = 0; b < Bc; ++b) {
        float V = 0.0f;
        if (seg != 0) {
            const bool g = (nprev > 0) && gate_or(prevf, nprev, c0 - 1);
            for (int t = t0 - 64; t < t0; ++t) {
                float u = (float)utok[((size_t)(t >> 5) * Bc + b) * UTS + e];
                if (g) u += (float)du[((size_t)t * Bc + b) * Dc + e];
                V = fmaf(bet, V, u);
            }
        }
        for (int j = 0; j < SEG / 64; ++j) {
            const bool g  = (nprev > 0) && gate_or(prevf, nprev, c0 + j);
            const bool wj = (f >> j) & 1;
            for (int k = 0; k < 64; ++k) {
                const int t = t0 + j * 64 + k;
                float u = (float)utok[((size_t)(t >> 5) * Bc + b) * UTS + e];
                if (g) u += (float)du[((size_t)t * Bc + b) * Dc + e];
                V = fmaf(bet, V, u);
                if (wj) spk[((size_t)t * Bc + b) * Dc + e] = (V >= vt) ? vtb : zb;
            }
        }
    }
}

// ---------------------------------------------------------------------------
// Output PLIF scan fused with K-frame mean. Clean chunks: h = htok[s] hoisted
// per token; dirty chunks: per-frame hframe. decoded is [b][s][d] bf16.
// ---------------------------------------------------------------------------
__global__ __launch_bounds__(256)
void out_scan(const float* __restrict__ htok, const float* __restrict__ hframe,
              const float* __restrict__ alpha_p, const float* __restrict__ beta,
              const float* __restrict__ vth, const int* __restrict__ flags,
              __bf16* __restrict__ decoded)
{
    const int d = blockIdx.x * 256 + threadIdx.x;
    const int b = blockIdx.y;
    const int seg = blockIdx.z;
    const float al  = alpha_p[0];
    const float bet = beta[d];
    const float vt  = vth[d];
    float V = 0.0f;
    const int t0 = seg * SEG;
    const int c0 = t0 >> 6;
    if (seg != 0) {
        const bool g = gate_or(flags, NLc, c0 - 1);
        if (!g) {
            for (int tk = (t0 >> 5) - 2; tk < (t0 >> 5); ++tk) {
                const float ah = al * htok[((size_t)tk * Bc + b) * Dc + d];
                for (int k = 0; k < 32; ++k) V = fmaf(bet, V, ah);
            }
        } else {
            for (int t = t0 - 64; t < t0; ++t)
                V = fmaf(bet, V, al * hframe[((size_t)t * Bc + b) * Dc + d]);
        }
    }
    for (int j = 0; j < SEG / 64; ++j) {
        const int c = c0 + j;
        const bool g = gate_or(flags, NLc, c);
        if (!g) {
            for (int ti = 0; ti < 2; ++ti) {
                const int tk = (t0 >> 5) + 2 * j + ti;
                const float ah = al * htok[((size_t)tk * Bc + b) * Dc + d];
                float sum = 0.0f;
                for (int k = 0; k < 32; ++k) {
                    V = fmaf(bet, V, ah);
                    sum += (V >= vt) ? vt : 0.0f;
                }
                decoded[((size_t)b * Sc + tk) * Dc + d] = (__bf16)(sum * (1.0f / 32.0f));
            }
        } else {
            float sum = 0.0f;
            for (int k = 0; k < 64; ++k) {
                const int t = t0 + j * 64 + k;
                V = fmaf(bet, V, al * hframe[((size_t)t * Bc + b) * Dc + d]);
                sum += (V >= vt) ? vt : 0.0f;
                if ((t & 31) == 31) {
                    const int s = t >> 5;
                    decoded[((size_t)b * Sc + s) * Dc + d] = (__bf16)(sum * (1.0f / 32.0f));
                    sum = 0.0f;
                }
            }
        }
    }
}

// ---------------------------------------------------------------------------
// Fused prep: role-partitioned by flat blockIdx.x (all independent):
//  [0,4096)      W_in  -> wT_in  (bf16 transpose, 32x32 tiles)
//  [4096,8192)   W_out -> wT_out
//  [8192,11264)  embed -> emb_bf (8 elems/thread)
//  [11264,11776) decode_w -> decw_bf
//  [11776,12288) token rows: h_tok = rmsnorm(embed[id]) * out_norm_w
// ---------------------------------------------------------------------------
__global__ __launch_bounds__(256)
void prep(const float* __restrict__ W_in, const float* __restrict__ W_out,
          const float* __restrict__ embed, const float* __restrict__ decode_w,
          const int* __restrict__ tok, const float* __restrict__ out_norm_w,
          __bf16* __restrict__ wT_in, __bf16* __restrict__ wT_out,
          __bf16* __restrict__ emb_bf, __bf16* __restrict__ decw_bf,
          float* __restrict__ h_tok)
{
    const int blk = blockIdx.x;
    const int tid = threadIdx.x;
    if (blk < 8192) {                       // W transpose+cast
        __shared__ float tile[32][33];
        const float* src = (blk < 4096) ? W_in  : W_out;
        __bf16*      dst = (blk < 4096) ? wT_in : wT_out;
        const int bb  = blk & 4095;
        const int mat = bb >> 10;
        const int t2  = bb & 1023;
        const int d0  = (t2 & 31) * 32, e0 = (t2 >> 5) * 32;
        const int tx = tid & 31, ty = tid >> 5;
        const float* Wm = src + (size_t)mat * Dc * Dc;
        __bf16*      Wo = dst + (size_t)mat * Dc * Dc;
#pragma unroll
        for (int i = 0; i < 4; ++i)
            tile[ty + i*8][tx] = Wm[(size_t)(d0 + ty + i*8) * Dc + e0 + tx];
        __syncthreads();
#pragma unroll
        for (int i = 0; i < 4; ++i)
            Wo[(size_t)(e0 + ty + i*8) * Dc + d0 + tx] = (__bf16)tile[tx][ty + i*8];
    } else if (blk < 11776) {               // casts (8 elems/thread)
        const float* src; __bf16* dst; int idx;
        if (blk < 11264) { src = embed;    dst = emb_bf;  idx = (blk - 8192) * 256 + tid; }
        else             { src = decode_w; dst = decw_bf; idx = (blk - 11264) * 256 + tid; }
        const f32x4* p = (const f32x4*)src + (size_t)idx * 2;
        f32x4 v0 = p[0], v1 = p[1];
        bf16x8 o;
        o[0]=(__bf16)v0[0]; o[1]=(__bf16)v0[1]; o[2]=(__bf16)v0[2]; o[3]=(__bf16)v0[3];
        o[4]=(__bf16)v1[0]; o[5]=(__bf16)v1[1]; o[6]=(__bf16)v1[2]; o[7]=(__bf16)v1[3];
        ((bf16x8*)dst)[idx] = o;
    } else {                                // h_tok rows
        const int r = blk - 11776;          // r = s*Bc + b
        const int s = r >> 1, b = r & 1;
        const int id = tok[b * Sc + s];
        const f32x4 v = ((const f32x4*)(embed + (size_t)id * Dc))[tid];
        float ss = v[0]*v[0] + v[1]*v[1] + v[2]*v[2] + v[3]*v[3];
#pragma unroll
        for (int off = 32; off >= 1; off >>= 1) ss += __shfl_down(ss, off);
        __shared__ float red[4];
        if ((tid & 63) == 0) red[tid >> 6] = ss;
        __syncthreads();
        float tot = red[0] + red[1] + red[2] + red[3];
        float sc = rsqrtf(tot * (1.0f / Dc) + 1e-6f);
        const f32x4 wv = ((const f32x4*)out_norm_w)[tid];
        f32x4 h = {v[0]*sc*wv[0], v[1]*sc*wv[1], v[2]*sc*wv[2], v[3]*sc*wv[3]};
        ((f32x4*)(h_tok + (size_t)r * Dc))[tid] = h;
    }
}

// hframe for dirty panels: x = emb + dx, per-row rmsnorm * out_norm_w.
__global__ __launch_bounds__(256)
void hframe_dirty(const int* __restrict__ tok, const float* __restrict__ embed,
                  const __bf16* __restrict__ dx, const float* __restrict__ w,
                  const int* __restrict__ flags, float* __restrict__ hf)
{
    const int panel = blockIdx.x;
    if (!gate_or(flags, NLc, panel)) return;
    const int tid = threadIdx.x;
    const f32x4 wv = ((const f32x4*)w)[tid];
    __shared__ float red[4];
    for (int i = 0; i < 16; ++i) {
        int r = panel * 128 + blockIdx.y * 16 + i;
        int t = r >> 1, b = r & 1, s = t >> 5;
        int id = tok[b * Sc + s];
        f32x4 v = ((const f32x4*)(embed + (size_t)id * Dc))[tid];
        bf16x4 dv = ((const bf16x4*)(dx + (size_t)r * Dc))[tid];
        v[0] += (float)dv[0]; v[1] += (float)dv[1];
        v[2] += (float)dv[2]; v[3] += (float)dv[3];
        float ss = v[0]*v[0] + v[1]*v[1] + v[2]*v[2] + v[3]*v[3];
#pragma unroll
        for (int off = 32; off >= 1; off >>= 1) ss += __shfl_down(ss, off);
        if ((tid & 63) == 0) red[tid >> 6] = ss;
        __syncthreads();
        float tot = red[0] + red[1] + red[2] + red[3];
        __syncthreads();
        float sc = rsqrtf(tot * (1.0f / Dc) + 1e-6f);
        f32x4 h = {v[0]*sc*wv[0], v[1]*sc*wv[1], v[2]*sc*wv[2], v[3]*sc*wv[3]};
        ((f32x4*)(hf + (size_t)r * Dc))[tid] = h;
    }
}

// RMSNorm over D=1024 per row -> bf16
__global__ __launch_bounds__(256)
void rmsnorm_rows(const float* __restrict__ in, const float* __restrict__ w,
                  __bf16* __restrict__ outb)
{
    const int r = blockIdx.x;
    const int tid = threadIdx.x;
    const f32x4 v = ((const f32x4*)(in + (size_t)r * Dc))[tid];
    float ss = v[0]*v[0] + v[1]*v[1] + v[2]*v[2] + v[3]*v[3];
#pragma unroll
    for (int off = 32; off >= 1; off >>= 1) ss += __shfl_down(ss, off);
    __shared__ float red[4];
    if ((tid & 63) == 0) red[tid >> 6] = ss;
    __syncthreads();
    float tot = red[0] + red[1] + red[2] + red[3];
    float sc = rsqrtf(tot * (1.0f / Dc) + 1e-6f);
    const f32x4 wv = ((const f32x4*)w)[tid];
    bf16x4 o;
    o[0]=(__bf16)(v[0]*sc*wv[0]); o[1]=(__bf16)(v[1]*sc*wv[1]);
    o[2]=(__bf16)(v[2]*sc*wv[2]); o[3]=(__bf16)(v[3]*sc*wv[3]);
    ((bf16x4*)(outb + (size_t)r * Dc))[tid] = o;
}

// ---------------------------------------------------------------------------
extern "C" void kernel_launch(void* const* d_in, const int* in_sizes, int n_in,
                              void* d_out, int out_size, void* d_ws, size_t ws_size,
                              hipStream_t stream)
{
    const int*   token_ids  = (const int*)  d_in[0];
    const float* embed      = (const float*)d_in[1];
    const float* W_in       = (const float*)d_in[2];
    const float* W_out      = (const float*)d_in[3];
    const float* layer_beta = (const float*)d_in[4];
    const float* layer_vth  = (const float*)d_in[5];
    const float* out_norm_w = (const float*)d_in[6];
    const float* out_beta   = (const float*)d_in[7];
    const float* out_vth    = (const float*)d_in[8];
    const float* out_alpha  = (const float*)d_in[9];
    const float* decode_w   = (const float*)d_in[10];
    const float* decode_b   = (const float*)d_in[11];
    const float* li_norm_w  = (const float*)d_in[12];
    float* out = (float*)d_out;

    size_t off = 0;
    auto alloc = [&](size_t bytes) -> void* {
        void* p = (char*)d_ws + off;
        off += (bytes + 255) & ~(size_t)255;
        return p;
    };
    float*  h_frame  = (float*) alloc((size_t)Tc * Bc * Dc * 4);   // dirty rows only
    __bf16* du       = (__bf16*)alloc((size_t)Tc * Bc * Dc * 2);   // dirty panels only
    __bf16* dx       = (__bf16*)alloc((size_t)Tc * Bc * Dc * 2);   // dirty panels only
    __bf16* spk      = (__bf16*)alloc((size_t)Tc * Bc * Dc * 2);   // flagged panels only
    __bf16* u_tokall = (__bf16*)alloc((size_t)Bc * Sc * UTS * 2);  // [512][4096]
    float*  h_tok    = (float*) alloc((size_t)Bc * Sc * Dc * 4);
    __bf16* wT_in    = (__bf16*)alloc((size_t)NLc * Dc * Dc * 2);
    __bf16* wT_out   = (__bf16*)alloc((size_t)NLc * Dc * Dc * 2);
    __bf16* emb_bf   = (__bf16*)alloc((size_t)Vc * Dc * 2);
    __bf16* decw_bf  = (__bf16*)alloc((size_t)Dc * Dc * 2);
    __bf16* decoded  = (__bf16*)alloc((size_t)Bc * Sc * Dc * 2);
    float*  h2       = (float*) alloc((size_t)Bc * Sc * Dc * 4);
    __bf16* h2n      = (__bf16*)alloc((size_t)Bc * Sc * Dc * 2);
    int*    flags    = (int*)   alloc((size_t)NLc * NPANEL * 4);   // per-layer spike flags

    // 1. fused prep (weights transpose/cast, embed/decw cast, h_tok)
    prep<<<12288, 256, 0, stream>>>(W_in, W_out, embed, decode_w, token_ids,
                                    out_norm_w, wT_in, wT_out, emb_bf, decw_bf,
                                    h_tok);

    // 2. all-layer token-level u in ONE GEMM, A gathered from emb_bf by token
    gemm_bt<3, 1><<<dim3(UTS / 128, (Bc * Sc) / 128), 256, 0, stream>>>(
        emb_bf, wT_in, Bc * Sc, UTS, Dc, nullptr, nullptr, u_tokall, nullptr,
        nullptr, nullptr, 0, token_ids);

    // 3. SNN layers: frame-level work only on dirty/spiking panels
    for (int l = 0; l < NLc; ++l) {
        if (l > 0) {   // du = dx @ W_in[l], only for panels dirtied by layers < l
            gemm_bt<4><<<dim3(Dc / 128, (Tc * Bc) / 128), 256, 0, stream>>>(
                dx, wT_in + (size_t)l * Dc * Dc, Tc * Bc, Dc, Dc,
                nullptr, nullptr, du, nullptr, nullptr, flags, l, nullptr);
        }
        scanA<<<NSEG, 1024, 0, stream>>>(
            u_tokall + (size_t)l * Dc, du, layer_beta + (size_t)l * Dc,
            layer_vth + (size_t)l * Dc, spk, flags + (size_t)l * NPANEL,
            flags, l);
        // dx += spk @ W_out[l], only for panels that spiked this layer
        gemm_bt<5><<<dim3(Dc / 128, (Tc * Bc) / 128), 256, 0, stream>>>(
            spk, wT_out + (size_t)l * Dc * Dc, Tc * Bc, Dc, Dc,
            nullptr, dx, nullptr, nullptr, flags + (size_t)l * NPANEL, flags, l,
            nullptr);
    }

    // 4. decode head
    hframe_dirty<<<dim3(NPANEL, 8), 256, 0, stream>>>(
        token_ids, embed, dx, out_norm_w, flags, h_frame);
    out_scan<<<dim3(Dc / 256, Bc, NSEG), 256, 0, stream>>>(
        h_tok, h_frame, out_alpha, out_beta, out_vth, flags, decoded);
    gemm_bt<2><<<dim3(Dc / 128, (Bc * Sc) / 128), 256, 0, stream>>>(
        decoded, decw_bf, Bc * Sc, Dc, Dc, h2, nullptr, nullptr, decode_b,
        nullptr, nullptr, 0, nullptr);
    rmsnorm_rows<<<Bc * Sc, 256, 0, stream>>>(h2, li_norm_w, h2n);
    gemm_bt<0><<<dim3(Vc / 128, (Bc * Sc) / 128), 256, 0, stream>>>(
        h2n, emb_bf, Bc * Sc, Vc, Dc, out, nullptr, nullptr, nullptr,
        nullptr, nullptr, 0, nullptr);
}

// Round 6
// 115.828 us; speedup vs baseline: 6.8197x; 1.1986x over previous
//
#include <hip/hip_runtime.h>

typedef __bf16 bf16x8 __attribute__((ext_vector_type(8)));
typedef __bf16 bf16x4 __attribute__((ext_vector_type(4)));
typedef __bf16 bf16x2 __attribute__((ext_vector_type(2)));
typedef float  f32x4  __attribute__((ext_vector_type(4)));

constexpr int Bc = 2, Sc = 256, Kc = 32, Tc = 8192, Dc = 1024, Vc = 6144, NLc = 4;
constexpr int SEG = 256, NSEG = Tc / SEG;
constexpr int NPANEL = (Tc * Bc) / 128;   // 128 panels (64 frames x both batches)
constexpr int UTS = NLc * Dc;             // u_tok_all row stride (4096)

__device__ __forceinline__ void gload16(const void* g, void* l) {
    __builtin_amdgcn_global_load_lds(
        (const __attribute__((address_space(1))) unsigned int*)g,
        (__attribute__((address_space(3))) unsigned int*)l,
        16, 0, 0);
}

// bijective XCD-aware block swizzle (m204 variant)
__device__ __forceinline__ int xcd_swz(int lin, int nwg) {
    int q = nwg >> 3, r = nwg & 7;
    int x = lin & 7, o = lin >> 3;
    int base = (x < r) ? x * (q + 1) : r * (q + 1) + (x - r) * q;
    return base + o;
}

// OR of n flag arrays (stride NPANEL) at panel p — uniform scalar loads
__device__ __forceinline__ bool gate_or(const int* f, int n, int p) {
    bool g = false;
    for (int j = 0; j < n; ++j) g = g || (f[j * NPANEL + p] != 0);
    return g;
}

// ---------------------------------------------------------------------------
// GEMM: C[M][N] = A[M][K] (bf16 rm) x BT[N][K] (bf16 rm), BMxBN tile, BK=64,
// 4 waves (2x2), mfma 16x16x32, swizzled LDS via pre-swizzled global src.
// GATHER: A row r -> row tok[(r&1)*Sc + (r>>1)] of A (token-level u GEMM).
// COLLOOP: 1-D grid over M-panels, inner loop over all column tiles
//          (cheap dispatch for mostly-early-exit gated GEMMs).
// EPI 0: Cout(f32)=acc                    EPI 2: Cout=acc+bias[col]
// EPI 3: outb=bf16(acc)
// EPI 4: [du]  exit if panel clean (OR prevf); outb=bf16(acc)
// EPI 5: [spk] exit if !exitf[panel]; dxio = bf16((prevdirty?dxio:0)+acc)
// ---------------------------------------------------------------------------
template<int EPI, int BM, int BN, int GATHER = 0, int COLLOOP = 0>
__global__ __launch_bounds__(256)
void gemm_bt(const __bf16* __restrict__ A, const __bf16* __restrict__ BT,
             int M, int N, int Kd,
             float* __restrict__ Cout, __bf16* __restrict__ dxio,
             __bf16* __restrict__ outb, const float* __restrict__ bias,
             const int* __restrict__ exitf, const int* __restrict__ prevf,
             int nprev, const int* __restrict__ tok)
{
    constexpr int MI = BM / 32;           // m-frags per wave
    constexpr int NI = BN / 32;           // n-frags per wave
    constexpr int CA = BM / 32;           // A staging chunks per thread
    constexpr int CB = BN / 32;           // B staging chunks per thread
    __shared__ char lds[(BM + BN) * 128];
    char* As = lds;
    char* Bs = lds + BM * 128;
    const int tid  = threadIdx.x;
    const int lane = tid & 63;
    const int wid  = tid >> 6;
    const int wm   = wid & 1, wn = wid >> 1;

    int bm, bn0 = 0;
    if (COLLOOP) {
        bm = blockIdx.x * BM;
    } else {
        const int nwg = gridDim.x * gridDim.y;
        const int lin = blockIdx.y * gridDim.x + blockIdx.x;
        const int swz = xcd_swz(lin, nwg);
        bn0 = (swz % gridDim.x) * BN;
        bm  = (swz / gridDim.x) * BM;
    }

    bool prevdirty = false;
    if (EPI == 4 || EPI == 5) prevdirty = gate_or(prevf, nprev, bm >> 7);
    if (EPI == 4 && !prevdirty) return;
    if (EPI == 5 && exitf[bm >> 7] == 0) return;

    // hoist A staging source addresses (constant across column tiles)
    const __bf16* asrc[CA];
#pragma unroll
    for (int i = 0; i < CA; ++i) {
        int chunk = i * 256 + tid;
        int row = chunk >> 3, kc = chunk & 7;
        int kcs = kc ^ (row & 7);             // pre-swizzled global source
        int gr = bm + row;
        const __bf16* abase;
        if (GATHER) {
            int id = tok[(gr & 1) * Sc + (gr >> 1)];
            abase = A + (size_t)id * Kd;
        } else {
            abase = A + (size_t)gr * Kd;
        }
        asrc[i] = abase + kcs * 8;
    }

    const int ncols = COLLOOP ? (N / BN) : 1;
    for (int nc = 0; nc < ncols; ++nc) {
        const int bn = COLLOOP ? nc * BN : bn0;
        const __bf16* bsrc[CB];
#pragma unroll
        for (int i = 0; i < CB; ++i) {
            int chunk = i * 256 + tid;
            int row = chunk >> 3, kc = chunk & 7;
            int kcs = kc ^ (row & 7);
            bsrc[i] = BT + (size_t)(bn + row) * Kd + kcs * 8;
        }

        f32x4 acc[MI][NI] = {};

        for (int kt = 0; kt < Kd; kt += 64) {
#pragma unroll
            for (int i = 0; i < CA; ++i)
                gload16(asrc[i] + kt, As + (i * 256 + tid) * 16);
#pragma unroll
            for (int i = 0; i < CB; ++i)
                gload16(bsrc[i] + kt, Bs + (i * 256 + tid) * 16);
            __syncthreads();
#pragma unroll
            for (int kk = 0; kk < 2; ++kk) {
                const int ko = kk * 64 + ((lane >> 4) << 4);
                bf16x8 af[MI], bfr[NI];
#pragma unroll
                for (int mi = 0; mi < MI; ++mi) {
                    int row = wm * (BM / 2) + mi * 16 + (lane & 15);
                    af[mi] = *(const bf16x8*)(As + row * 128 + (ko ^ ((row & 7) << 4)));
                }
#pragma unroll
                for (int ni = 0; ni < NI; ++ni) {
                    int row = wn * (BN / 2) + ni * 16 + (lane & 15);
                    bfr[ni] = *(const bf16x8*)(Bs + row * 128 + (ko ^ ((row & 7) << 4)));
                }
#pragma unroll
                for (int mi = 0; mi < MI; ++mi)
#pragma unroll
                    for (int ni = 0; ni < NI; ++ni)
                        acc[mi][ni] = __builtin_amdgcn_mfma_f32_16x16x32_bf16(
                            af[mi], bfr[ni], acc[mi][ni], 0, 0, 0);
            }
            __syncthreads();
        }

        const int cc = lane & 15, cr = (lane >> 4) * 4;
#pragma unroll
        for (int mi = 0; mi < MI; ++mi) {
#pragma unroll
            for (int ni = 0; ni < NI; ++ni) {
                int gcol = bn + wn * (BN / 2) + ni * 16 + cc;
#pragma unroll
                for (int r = 0; r < 4; ++r) {
                    int grow = bm + wm * (BM / 2) + mi * 16 + cr + r;
                    size_t idx = (size_t)grow * N + gcol;
                    float v = acc[mi][ni][r];
                    if (EPI == 0) {
                        Cout[idx] = v;
                    } else if (EPI == 2) {
                        Cout[idx] = v + bias[gcol];
                    } else if (EPI == 3 || EPI == 4) {
                        outb[idx] = (__bf16)v;
                    } else if (EPI == 5) {
                        float base = prevdirty ? (float)dxio[idx] : 0.0f;
                        dxio[idx] = (__bf16)(base + v);
                    }
                }
            }
        }
    }
}

// ---------------------------------------------------------------------------
// Fused PLIF scan: flags + gated spike write in ONE kernel (one block/segment).
// Clean chunks: exact closed form (V32 = a32*V + u*S32, monotone -> endpoints).
// ---------------------------------------------------------------------------
__global__ __launch_bounds__(1024)
void scanA(const __bf16* __restrict__ utok, const __bf16* __restrict__ du,
           const float* __restrict__ beta, const float* __restrict__ vth,
           __bf16* __restrict__ spk, int* __restrict__ flags_l,
           const int* __restrict__ prevf, int nprev)
{
    const int e   = threadIdx.x;
    const int seg = blockIdx.x;
    const int t0  = seg * SEG;
    const int c0  = t0 >> 6;
    const float bet = beta[e];
    const float vt  = vth[e];
    float a = bet, S = 1.0f;                 // -> a=beta^32, S=S32 (5 doublings)
#pragma unroll
    for (int i = 0; i < 5; ++i) { S = S * (1.0f + a); a = a * a; }

    __shared__ int fm;
    if (e == 0) fm = 0;
    __syncthreads();

    unsigned mask = 0;
    for (int b = 0; b < Bc; ++b) {
        float V = 0.0f;
        if (seg != 0) {
            const bool g = (nprev > 0) && gate_or(prevf, nprev, c0 - 1);
            if (!g) {
                const int tk0 = (t0 >> 5) - 2;
#pragma unroll
                for (int ti = 0; ti < 2; ++ti) {
                    float u = (float)utok[((size_t)(tk0 + ti) * Bc + b) * UTS + e];
                    V = fmaf(a, V, u * S);
                }
            } else {
                for (int t = t0 - 64; t < t0; ++t) {
                    float u = (float)utok[((size_t)(t >> 5) * Bc + b) * UTS + e]
                            + (float)du[((size_t)t * Bc + b) * Dc + e];
                    V = fmaf(bet, V, u);
                }
            }
        }
        for (int j = 0; j < SEG / 64; ++j) {
            const bool g = (nprev > 0) && gate_or(prevf, nprev, c0 + j);
            if (!g) {
                float mx = -1e30f;
#pragma unroll
                for (int ti = 0; ti < 2; ++ti) {
                    const int tk = (t0 >> 5) + 2 * j + ti;
                    float u  = (float)utok[((size_t)tk * Bc + b) * UTS + e];
                    float V1 = fmaf(bet, V, u);          // first step of window
                    V = fmaf(a, V, u * S);               // after 32 steps
                    mx = fmaxf(mx, fmaxf(V1, V));        // monotone => endpoints
                }
                if (mx >= vt) mask |= 1u << j;
            } else {
                bool any = false;
                for (int k = 0; k < 64; ++k) {
                    const int t = t0 + j * 64 + k;
                    float u = (float)utok[((size_t)(t >> 5) * Bc + b) * UTS + e]
                            + (float)du[((size_t)t * Bc + b) * Dc + e];
                    V = fmaf(bet, V, u);
                    any = any || (V >= vt);
                }
                if (any) mask |= 1u << j;
            }
        }
    }
    if (mask) atomicOr(&fm, (int)mask);
    __syncthreads();
    const int f = fm;
    if (e < SEG / 64) flags_l[c0 + e] = (f >> e) & 1;   // exclusive owner
    if (f == 0) return;

    // ---- spike write phase (rare): stepwise recompute, write flagged chunks
    const __bf16 vtb = (__bf16)vt;
    const __bf16 zb  = (__bf16)0.0f;
    for (int b = 0; b < Bc; ++b) {
        float V = 0.0f;
        if (seg != 0) {
            const bool g = (nprev > 0) && gate_or(prevf, nprev, c0 - 1);
            for (int t = t0 - 64; t < t0; ++t) {
                float u = (float)utok[((size_t)(t >> 5) * Bc + b) * UTS + e];
                if (g) u += (float)du[((size_t)t * Bc + b) * Dc + e];
                V = fmaf(bet, V, u);
            }
        }
        for (int j = 0; j < SEG / 64; ++j) {
            const bool g  = (nprev > 0) && gate_or(prevf, nprev, c0 + j);
            const bool wj = (f >> j) & 1;
            for (int k = 0; k < 64; ++k) {
                const int t = t0 + j * 64 + k;
                float u = (float)utok[((size_t)(t >> 5) * Bc + b) * UTS + e];
                if (g) u += (float)du[((size_t)t * Bc + b) * Dc + e];
                V = fmaf(bet, V, u);
                if (wj) spk[((size_t)t * Bc + b) * Dc + e] = (V >= vt) ? vtb : zb;
            }
        }
    }
}

// ---------------------------------------------------------------------------
// Token-parallel output PLIF scan + K-frame mean. One block per (d-group,b,s).
// Clean window: 2-token closed-form warm-up + 32 stepwise (exact: beta^64
// below f32 ulp). Dirty window: stepwise over 64-frame warm-up + 32 main.
// ---------------------------------------------------------------------------
__global__ __launch_bounds__(256)
void out_scan_tok(const float* __restrict__ htok, const float* __restrict__ hframe,
                  const float* __restrict__ alpha_p, const float* __restrict__ beta,
                  const float* __restrict__ vth, const int* __restrict__ flags,
                  __bf16* __restrict__ decoded)
{
    const int d = blockIdx.x * 256 + threadIdx.x;
    const int b = blockIdx.y;
    const int s = blockIdx.z;
    const float al  = alpha_p[0];
    const float bet = beta[d];
    const float vt  = vth[d];
    float a = bet, S = 1.0f;
#pragma unroll
    for (int i = 0; i < 5; ++i) { S = S * (1.0f + a); a = a * a; }

    const int t0 = s * Kc;
    const int tlo = (t0 >= 64) ? t0 - 64 : 0;
    const int clo = tlo >> 6, chi = (t0 + Kc - 1) >> 6;
    bool dirty = false;
    for (int c = clo; c <= chi; ++c) dirty = dirty || gate_or(flags, NLc, c);

    float V = 0.0f, sum = 0.0f;
    if (!dirty) {
        const int sk0 = (s >= 2) ? s - 2 : 0;
        for (int tk = sk0; tk < s; ++tk) {
            float ah = al * htok[((size_t)tk * Bc + b) * Dc + d];
            V = fmaf(a, V, ah * S);
        }
        const float ah = al * htok[((size_t)s * Bc + b) * Dc + d];
        for (int k = 0; k < Kc; ++k) {
            V = fmaf(bet, V, ah);
            sum += (V >= vt) ? vt : 0.0f;
        }
    } else {
        for (int t = tlo; t < t0 + Kc; ++t) {
            const bool g = gate_or(flags, NLc, t >> 6);
            float h = g ? hframe[((size_t)t * Bc + b) * Dc + d]
                        : htok[((size_t)(t >> 5) * Bc + b) * Dc + d];
            V = fmaf(bet, V, al * h);
            if (t >= t0) sum += (V >= vt) ? vt : 0.0f;
        }
    }
    decoded[((size_t)b * Sc + s) * Dc + d] = (__bf16)(sum * (1.0f / 32.0f));
}

// ---------------------------------------------------------------------------
// Fused prep, role-partitioned by flat blockIdx.x:
//  [0,4096)      W_in  -> wT_in  (bf16 transpose, 32x32 tiles)
//  [4096,8192)   W_out -> wT_out
//  [8192,11264)  embed -> emb_bf (8 elems/thread)
//  [11264,11776) decode_w -> decw_bf
//  [11776,12288) token rows: h_tok = rmsnorm(embed[id]) * out_norm_w
//                (first such block also zeroes the flag array)
// ---------------------------------------------------------------------------
__global__ __launch_bounds__(256)
void prep(const float* __restrict__ W_in, const float* __restrict__ W_out,
          const float* __restrict__ embed, const float* __restrict__ decode_w,
          const int* __restrict__ tok, const float* __restrict__ out_norm_w,
          __bf16* __restrict__ wT_in, __bf16* __restrict__ wT_out,
          __bf16* __restrict__ emb_bf, __bf16* __restrict__ decw_bf,
          float* __restrict__ h_tok, int* __restrict__ flags)
{
    const int blk = blockIdx.x;
    const int tid = threadIdx.x;
    if (blk < 8192) {                       // W transpose+cast
        __shared__ float tile[32][33];
        const float* src = (blk < 4096) ? W_in  : W_out;
        __bf16*      dst = (blk < 4096) ? wT_in : wT_out;
        const int bb  = blk & 4095;
        const int mat = bb >> 10;
        const int t2  = bb & 1023;
        const int d0  = (t2 & 31) * 32, e0 = (t2 >> 5) * 32;
        const float* Wm = src + (size_t)mat * Dc * Dc;
        __bf16*      Wo = dst + (size_t)mat * Dc * Dc;
        const int tx = tid & 31, ty = tid >> 5;
#pragma unroll
        for (int i = 0; i < 4; ++i)
            tile[ty + i*8][tx] = Wm[(size_t)(d0 + ty + i*8) * Dc + e0 + tx];
        __syncthreads();
        const int txp = tid & 15, tyw = tid >> 4;   // col-pair, 16 rows
#pragma unroll
        for (int i = 0; i < 2; ++i) {
            int r = tyw + 16 * i;                   // e-dim row in tile
            bf16x2 o;
            o[0] = (__bf16)tile[2*txp][r];
            o[1] = (__bf16)tile[2*txp + 1][r];
            *(bf16x2*)(&Wo[(size_t)(e0 + r) * Dc + d0 + 2*txp]) = o;
        }
    } else if (blk < 11776) {               // casts (8 elems/thread)
        const float* src; __bf16* dst; int idx;
        if (blk < 11264) { src = embed;    dst = emb_bf;  idx = (blk - 8192) * 256 + tid; }
        else             { src = decode_w; dst = decw_bf; idx = (blk - 11264) * 256 + tid; }
        const f32x4* p = (const f32x4*)src + (size_t)idx * 2;
        f32x4 v0 = p[0], v1 = p[1];
        bf16x8 o;
        o[0]=(__bf16)v0[0]; o[1]=(__bf16)v0[1]; o[2]=(__bf16)v0[2]; o[3]=(__bf16)v0[3];
        o[4]=(__bf16)v1[0]; o[5]=(__bf16)v1[1]; o[6]=(__bf16)v1[2]; o[7]=(__bf16)v1[3];
        ((bf16x8*)dst)[idx] = o;
    } else {                                // h_tok rows (+ flag zeroing)
        const int r = blk - 11776;          // r = s*Bc + b
        if (r == 0) { flags[tid] = 0; flags[tid + 256] = 0; }
        const int s = r >> 1, b = r & 1;
        const int id = tok[b * Sc + s];
        const f32x4 v = ((const f32x4*)(embed + (size_t)id * Dc))[tid];
        float ss = v[0]*v[0] + v[1]*v[1] + v[2]*v[2] + v[3]*v[3];
#pragma unroll
        for (int off = 32; off >= 1; off >>= 1) ss += __shfl_down(ss, off);
        __shared__ float red[4];
        if ((tid & 63) == 0) red[tid >> 6] = ss;
        __syncthreads();
        float tot = red[0] + red[1] + red[2] + red[3];
        float sc = rsqrtf(tot * (1.0f / Dc) + 1e-6f);
        const f32x4 wv = ((const f32x4*)out_norm_w)[tid];
        f32x4 h = {v[0]*sc*wv[0], v[1]*sc*wv[1], v[2]*sc*wv[2], v[3]*sc*wv[3]};
        ((f32x4*)(h_tok + (size_t)r * Dc))[tid] = h;
    }
}

// hframe for dirty panels: x = emb + dx, per-row rmsnorm * out_norm_w.
// grid (NPANEL, 2): block handles 64 rows of its panel; exits if clean.
__global__ __launch_bounds__(256)
void hframe_dirty(const int* __restrict__ tok, const float* __restrict__ embed,
                  const __bf16* __restrict__ dx, const float* __restrict__ w,
                  const int* __restrict__ flags, float* __restrict__ hf)
{
    const int panel = blockIdx.x;
    if (!gate_or(flags, NLc, panel)) return;
    const int tid = threadIdx.x;
    const f32x4 wv = ((const f32x4*)w)[tid];
    __shared__ float red[4];
    for (int i = 0; i < 64; ++i) {
        int r = panel * 128 + blockIdx.y * 64 + i;
        int t = r >> 1, b = r & 1, s = t >> 5;
        int id = tok[b * Sc + s];
        f32x4 v = ((const f32x4*)(embed + (size_t)id * Dc))[tid];
        bf16x4 dv = ((const bf16x4*)(dx + (size_t)r * Dc))[tid];
        v[0] += (float)dv[0]; v[1] += (float)dv[1];
        v[2] += (float)dv[2]; v[3] += (float)dv[3];
        float ss = v[0]*v[0] + v[1]*v[1] + v[2]*v[2] + v[3]*v[3];
#pragma unroll
        for (int off = 32; off >= 1; off >>= 1) ss += __shfl_down(ss, off);
        if ((tid & 63) == 0) red[tid >> 6] = ss;
        __syncthreads();
        float tot = red[0] + red[1] + red[2] + red[3];
        __syncthreads();
        float sc = rsqrtf(tot * (1.0f / Dc) + 1e-6f);
        f32x4 h = {v[0]*sc*wv[0], v[1]*sc*wv[1], v[2]*sc*wv[2], v[3]*sc*wv[3]};
        ((f32x4*)(hf + (size_t)r * Dc))[tid] = h;
    }
}

// RMSNorm over D=1024 per row -> bf16
__global__ __launch_bounds__(256)
void rmsnorm_rows(const float* __restrict__ in, const float* __restrict__ w,
                  __bf16* __restrict__ outb)
{
    const int r = blockIdx.x;
    const int tid = threadIdx.x;
    const f32x4 v = ((const f32x4*)(in + (size_t)r * Dc))[tid];
    float ss = v[0]*v[0] + v[1]*v[1] + v[2]*v[2] + v[3]*v[3];
#pragma unroll
    for (int off = 32; off >= 1; off >>= 1) ss += __shfl_down(ss, off);
    __shared__ float red[4];
    if ((tid & 63) == 0) red[tid >> 6] = ss;
    __syncthreads();
    float tot = red[0] + red[1] + red[2] + red[3];
    float sc = rsqrtf(tot * (1.0f / Dc) + 1e-6f);
    const f32x4 wv = ((const f32x4*)w)[tid];
    bf16x4 o;
    o[0]=(__bf16)(v[0]*sc*wv[0]); o[1]=(__bf16)(v[1]*sc*wv[1]);
    o[2]=(__bf16)(v[2]*sc*wv[2]); o[3]=(__bf16)(v[3]*sc*wv[3]);
    ((bf16x4*)(outb + (size_t)r * Dc))[tid] = o;
}

// ---------------------------------------------------------------------------
extern "C" void kernel_launch(void* const* d_in, const int* in_sizes, int n_in,
                              void* d_out, int out_size, void* d_ws, size_t ws_size,
                              hipStream_t stream)
{
    const int*   token_ids  = (const int*)  d_in[0];
    const float* embed      = (const float*)d_in[1];
    const float* W_in       = (const float*)d_in[2];
    const float* W_out      = (const float*)d_in[3];
    const float* layer_beta = (const float*)d_in[4];
    const float* layer_vth  = (const float*)d_in[5];
    const float* out_norm_w = (const float*)d_in[6];
    const float* out_beta   = (const float*)d_in[7];
    const float* out_vth    = (const float*)d_in[8];
    const float* out_alpha  = (const float*)d_in[9];
    const float* decode_w   = (const float*)d_in[10];
    const float* decode_b   = (const float*)d_in[11];
    const float* li_norm_w  = (const float*)d_in[12];
    float* out = (float*)d_out;

    size_t off = 0;
    auto alloc = [&](size_t bytes) -> void* {
        void* p = (char*)d_ws + off;
        off += (bytes + 255) & ~(size_t)255;
        return p;
    };
    float*  h_frame  = (float*) alloc((size_t)Tc * Bc * Dc * 4);   // dirty rows only
    __bf16* du       = (__bf16*)alloc((size_t)Tc * Bc * Dc * 2);   // dirty panels only
    __bf16* dx       = (__bf16*)alloc((size_t)Tc * Bc * Dc * 2);   // dirty panels only
    __bf16* spk      = (__bf16*)alloc((size_t)Tc * Bc * Dc * 2);   // flagged panels only
    __bf16* u_tokall = (__bf16*)alloc((size_t)Bc * Sc * UTS * 2);  // [512][4096]
    float*  h_tok    = (float*) alloc((size_t)Bc * Sc * Dc * 4);
    __bf16* wT_in    = (__bf16*)alloc((size_t)NLc * Dc * Dc * 2);
    __bf16* wT_out   = (__bf16*)alloc((size_t)NLc * Dc * Dc * 2);
    __bf16* emb_bf   = (__bf16*)alloc((size_t)Vc * Dc * 2);
    __bf16* decw_bf  = (__bf16*)alloc((size_t)Dc * Dc * 2);
    __bf16* decoded  = (__bf16*)alloc((size_t)Bc * Sc * Dc * 2);
    float*  h2       = (float*) alloc((size_t)Bc * Sc * Dc * 4);
    __bf16* h2n      = (__bf16*)alloc((size_t)Bc * Sc * Dc * 2);
    int*    flags    = (int*)   alloc((size_t)NLc * NPANEL * 4);   // per-layer spike flags

    // 1. fused prep
    prep<<<12288, 256, 0, stream>>>(W_in, W_out, embed, decode_w, token_ids,
                                    out_norm_w, wT_in, wT_out, emb_bf, decw_bf,
                                    h_tok, flags);

    // 2. all-layer token-level u in ONE GEMM (64x128 tiles -> 256 blocks)
    gemm_bt<3, 64, 128, 1><<<dim3(UTS / 128, (Bc * Sc) / 64), 256, 0, stream>>>(
        emb_bf, wT_in, Bc * Sc, UTS, Dc, nullptr, nullptr, u_tokall, nullptr,
        nullptr, nullptr, 0, token_ids);

    // 3. SNN layers: frame-level work only on dirty/spiking panels
    for (int l = 0; l < NLc; ++l) {
        if (l > 0) {   // du = dx @ W_in[l], gated per panel (128-WG colloop)
            gemm_bt<4, 128, 128, 0, 1><<<NPANEL, 256, 0, stream>>>(
                dx, wT_in + (size_t)l * Dc * Dc, Tc * Bc, Dc, Dc,
                nullptr, nullptr, du, nullptr, nullptr, flags, l, nullptr);
        }
        scanA<<<NSEG, 1024, 0, stream>>>(
            u_tokall + (size_t)l * Dc, du, layer_beta + (size_t)l * Dc,
            layer_vth + (size_t)l * Dc, spk, flags + (size_t)l * NPANEL,
            flags, l);
        // dx += spk @ W_out[l], gated per panel (128-WG colloop)
        gemm_bt<5, 128, 128, 0, 1><<<NPANEL, 256, 0, stream>>>(
            spk, wT_out + (size_t)l * Dc * Dc, Tc * Bc, Dc, Dc,
            nullptr, dx, nullptr, nullptr, flags + (size_t)l * NPANEL, flags, l,
            nullptr);
    }

    // 4. decode head
    hframe_dirty<<<dim3(NPANEL, 2), 256, 0, stream>>>(
        token_ids, embed, dx, out_norm_w, flags, h_frame);
    out_scan_tok<<<dim3(Dc / 256, Bc, Sc), 256, 0, stream>>>(
        h_tok, h_frame, out_alpha, out_beta, out_vth, flags, decoded);
    gemm_bt<2, 64, 64><<<dim3(Dc / 64, (Bc * Sc) / 64), 256, 0, stream>>>(
        decoded, decw_bf, Bc * Sc, Dc, Dc, h2, nullptr, nullptr, decode_b,
        nullptr, nullptr, 0, nullptr);
    rmsnorm_rows<<<Bc * Sc, 256, 0, stream>>>(h2, li_norm_w, h2n);
    gemm_bt<0, 64, 128><<<dim3(Vc / 128, (Bc * Sc) / 64), 256, 0, stream>>>(
        h2n, emb_bf, Bc * Sc, Vc, Dc, out, nullptr, nullptr, nullptr,
        nullptr, nullptr, 0, nullptr);
}

// Round 7
// 109.039 us; speedup vs baseline: 7.2443x; 1.0623x over previous
//
#include <hip/hip_runtime.h>

typedef __bf16 bf16x8 __attribute__((ext_vector_type(8)));
typedef __bf16 bf16x4 __attribute__((ext_vector_type(4)));
typedef __bf16 bf16x2 __attribute__((ext_vector_type(2)));
typedef float  f32x4  __attribute__((ext_vector_type(4)));

constexpr int Bc = 2, Sc = 256, Kc = 32, Tc = 8192, Dc = 1024, Vc = 6144, NLc = 4;
constexpr int SEG = 256, NSEG = Tc / SEG;
constexpr int NPANEL = (Tc * Bc) / 128;   // 128 chunks (64 frames x both batches)
constexpr int UTS = NLc * Dc;             // u_tok_all row stride (4096)

__device__ __forceinline__ void gload16(const void* g, void* l) {
    __builtin_amdgcn_global_load_lds(
        (const __attribute__((address_space(1))) unsigned int*)g,
        (__attribute__((address_space(3))) unsigned int*)l,
        16, 0, 0);
}

// bijective XCD-aware block swizzle (m204 variant)
__device__ __forceinline__ int xcd_swz(int lin, int nwg) {
    int q = nwg >> 3, r = nwg & 7;
    int x = lin & 7, o = lin >> 3;
    int base = (x < r) ? x * (q + 1) : r * (q + 1) + (x - r) * q;
    return base + o;
}

// OR of n flag arrays (stride NPANEL) at chunk p
__device__ __forceinline__ bool gate_or(const int* f, int n, int p) {
    bool g = false;
    for (int j = 0; j < n; ++j) g = g || (f[j * NPANEL + p] != 0);
    return g;
}

// ---------------------------------------------------------------------------
// GEMM: C[M][N] = A[M][K](bf16 rm) x BT[N][K], BMxBN tile, BK=64, 4 waves,
// mfma 16x16x32, swizzled LDS. A staged via pre-swizzled-source gload_lds.
// BSRC 0: BT bf16 via gload_lds.  BSRC 1: BTf f32, reg-staged cast+ds_write.
// EPI 0: Cout=acc   EPI 2: Cout=acc+bias[col]   EPI 3: outb=bf16(acc)
// ---------------------------------------------------------------------------
template<int EPI, int BM, int BN, int BSRC>
__global__ __launch_bounds__(256)
void gemm_bt(const __bf16* __restrict__ A, const __bf16* __restrict__ BT,
             const float* __restrict__ BTf, int M, int N, int Kd,
             float* __restrict__ Cout, __bf16* __restrict__ outb,
             const float* __restrict__ bias)
{
    constexpr int MI = BM / 32, NI = BN / 32;
    constexpr int CA = BM / 32, CB = BN / 32;
    __shared__ char lds[(BM + BN) * 128];
    char* As = lds;
    char* Bs = lds + BM * 128;
    const int tid  = threadIdx.x;
    const int lane = tid & 63;
    const int wid  = tid >> 6;
    const int wm   = wid & 1, wn = wid >> 1;

    const int nwg = gridDim.x * gridDim.y;
    const int lin = blockIdx.y * gridDim.x + blockIdx.x;
    const int swz = xcd_swz(lin, nwg);
    const int bn  = (swz % gridDim.x) * BN;
    const int bm  = (swz / gridDim.x) * BM;

    const __bf16* asrc[CA];
#pragma unroll
    for (int i = 0; i < CA; ++i) {
        int chunk = i * 256 + tid;
        int row = chunk >> 3, kc = chunk & 7;
        int kcs = kc ^ (row & 7);
        asrc[i] = A + (size_t)(bm + row) * Kd + kcs * 8;
    }
    const __bf16* bsrc[CB];
    if (BSRC == 0) {
#pragma unroll
        for (int i = 0; i < CB; ++i) {
            int chunk = i * 256 + tid;
            int row = chunk >> 3, kc = chunk & 7;
            int kcs = kc ^ (row & 7);
            bsrc[i] = BT + (size_t)(bn + row) * Kd + kcs * 8;
        }
    }

    f32x4 acc[MI][NI] = {};

    for (int kt = 0; kt < Kd; kt += 64) {
#pragma unroll
        for (int i = 0; i < CA; ++i)
            gload16(asrc[i] + kt, As + (i * 256 + tid) * 16);
        if (BSRC == 0) {
#pragma unroll
            for (int i = 0; i < CB; ++i)
                gload16(bsrc[i] + kt, Bs + (i * 256 + tid) * 16);
        } else {
#pragma unroll
            for (int i = 0; i < CB; ++i) {
                int unit = i * 256 + tid;
                int row = unit >> 3, kc = unit & 7;
                const float* src = BTf + (size_t)(bn + row) * Kd + kt + kc * 8;
                f32x4 v0 = *(const f32x4*)src;
                f32x4 v1 = *(const f32x4*)(src + 4);
                bf16x8 o;
                o[0]=(__bf16)v0[0]; o[1]=(__bf16)v0[1]; o[2]=(__bf16)v0[2]; o[3]=(__bf16)v0[3];
                o[4]=(__bf16)v1[0]; o[5]=(__bf16)v1[1]; o[6]=(__bf16)v1[2]; o[7]=(__bf16)v1[3];
                *(bf16x8*)(Bs + row * 128 + ((kc * 16) ^ ((row & 7) << 4))) = o;
            }
        }
        __syncthreads();
#pragma unroll
        for (int kk = 0; kk < 2; ++kk) {
            const int ko = kk * 64 + ((lane >> 4) << 4);
            bf16x8 af[MI], bfr[NI];
#pragma unroll
            for (int mi = 0; mi < MI; ++mi) {
                int row = wm * (BM / 2) + mi * 16 + (lane & 15);
                af[mi] = *(const bf16x8*)(As + row * 128 + (ko ^ ((row & 7) << 4)));
            }
#pragma unroll
            for (int ni = 0; ni < NI; ++ni) {
                int row = wn * (BN / 2) + ni * 16 + (lane & 15);
                bfr[ni] = *(const bf16x8*)(Bs + row * 128 + (ko ^ ((row & 7) << 4)));
            }
#pragma unroll
            for (int mi = 0; mi < MI; ++mi)
#pragma unroll
                for (int ni = 0; ni < NI; ++ni)
                    acc[mi][ni] = __builtin_amdgcn_mfma_f32_16x16x32_bf16(
                        af[mi], bfr[ni], acc[mi][ni], 0, 0, 0);
        }
        __syncthreads();
    }

    const int cc = lane & 15, cr = (lane >> 4) * 4;
#pragma unroll
    for (int mi = 0; mi < MI; ++mi) {
#pragma unroll
        for (int ni = 0; ni < NI; ++ni) {
            int gcol = bn + wn * (BN / 2) + ni * 16 + cc;
#pragma unroll
            for (int r = 0; r < 4; ++r) {
                int grow = bm + wm * (BM / 2) + mi * 16 + cr + r;
                size_t idx = (size_t)grow * N + gcol;
                float v = acc[mi][ni][r];
                if (EPI == 0)      Cout[idx] = v;
                else if (EPI == 2) Cout[idx] = v + bias[gcol];
                else               outb[idx] = (__bf16)v;
            }
        }
    }
}

// ---------------------------------------------------------------------------
// Fused per-layer SNN step: flag scan + in-kernel du recompute (dirty chunks)
// + in-kernel dx update (flagged chunks) + dirty-chunk copy-forward.
// One block per segment (1024 threads = all e). dx ping-pong dxR -> dxW so
// phase-1 reads never race phase-2 writes across blocks.
// Clean chunks use the exact closed form (V32 = a32*V + u*S32, monotone).
// Dirty/flagged fallback is VALU (rare; correctness-only).
// ---------------------------------------------------------------------------
__global__ __launch_bounds__(1024)
void fused_layer(const __bf16* __restrict__ utok, const float* __restrict__ Win,
                 const float* __restrict__ Wout, const float* __restrict__ beta,
                 const float* __restrict__ vth, const __bf16* __restrict__ dxR,
                 __bf16* __restrict__ dxW, int* __restrict__ flags_all, int l)
{
    const int e   = threadIdx.x;
    const int seg = blockIdx.x;
    const int t0  = seg * SEG, c0 = t0 >> 6;
    const float bet = beta[e], vt = vth[e];
    float a = bet, S = 1.0f;
#pragma unroll
    for (int i = 0; i < 5; ++i) { S = S * (1.0f + a); a = a * a; }
    int* flags_l = flags_all + l * NPANEL;

    __shared__ int fm;
    __shared__ __bf16 srow[Dc];
    if (e == 0) fm = 0;
    __syncthreads();

    bool pd[4];
    for (int j = 0; j < 4; ++j) pd[j] = gate_or(flags_all, l, c0 + j);
    const bool pdw = (seg != 0) && gate_or(flags_all, l, c0 - 1);

    auto du_at = [&](int t, int b) -> float {   // dirty-chunk du (uniform calls)
        __syncthreads();
        srow[e] = dxR[((size_t)t * Bc + b) * Dc + e];
        __syncthreads();
        float acc = 0.f;
        for (int d = 0; d < Dc; ++d)
            acc = fmaf((float)srow[d], Win[(size_t)d * Dc + e], acc);
        return acc;
    };
    auto ut = [&](int tk, int b) -> float {
        return (float)utok[((size_t)tk * Bc + b) * UTS + e];
    };

    // ---- phase 1: flags
    unsigned mask = 0;
    for (int b = 0; b < Bc; ++b) {
        float V = 0.f;
        if (seg != 0) {
            if (!pdw) {
                const int tk0 = (t0 >> 5) - 2;
                for (int ti = 0; ti < 2; ++ti) V = fmaf(a, V, ut(tk0 + ti, b) * S);
            } else {
                for (int t = t0 - 64; t < t0; ++t)
                    V = fmaf(bet, V, ut(t >> 5, b) + du_at(t, b));
            }
        }
        for (int j = 0; j < 4; ++j) {
            if (!pd[j]) {
                float mx = -1e30f;
                for (int ti = 0; ti < 2; ++ti) {
                    const float u = ut((t0 >> 5) + 2 * j + ti, b);
                    float V1 = fmaf(bet, V, u);
                    V = fmaf(a, V, u * S);
                    mx = fmaxf(mx, fmaxf(V1, V));
                }
                if (mx >= vt) mask |= 1u << j;
            } else {
                bool any = false;
                for (int k = 0; k < 64; ++k) {
                    const int t = t0 + j * 64 + k;
                    V = fmaf(bet, V, ut(t >> 5, b) + du_at(t, b));
                    any = any || (V >= vt);
                }
                if (any) mask |= 1u << j;
            }
        }
    }
    if (mask) atomicOr(&fm, (int)mask);
    __syncthreads();
    const int f = fm;
    if (e < 4) flags_l[c0 + e] = (f >> e) & 1;

    bool needcopy = false;
    for (int j = 0; j < 4; ++j) needcopy = needcopy || (pd[j] && !((f >> j) & 1));
    if (f == 0 && !needcopy) return;

    // ---- copy-forward: dirty chunks that didn't spike this layer
    for (int j = 0; j < 4; ++j) {
        if (pd[j] && !((f >> j) & 1)) {
            int rbase = (t0 + j * 64) * Bc;
            for (int rr = 0; rr < 128; ++rr)
                dxW[(size_t)(rbase + rr) * Dc + e] = dxR[(size_t)(rbase + rr) * Dc + e];
        }
    }
    if (f == 0) return;

    // ---- phase 2: spike recompute + dx update for flagged chunks
    const __bf16 vtb = (__bf16)vt, zb = (__bf16)0.f;
    for (int b = 0; b < Bc; ++b) {
        float V = 0.f;
        if (seg != 0) {
            if (!pdw) {
                const int tk0 = (t0 >> 5) - 2;
                for (int ti = 0; ti < 2; ++ti) V = fmaf(a, V, ut(tk0 + ti, b) * S);
            } else {
                for (int t = t0 - 64; t < t0; ++t)
                    V = fmaf(bet, V, ut(t >> 5, b) + du_at(t, b));
            }
        }
        for (int j = 0; j < 4; ++j) {
            const bool wj = (f >> j) & 1;
            if (!wj && !pd[j]) {       // clean & unflagged: closed-form advance
                for (int ti = 0; ti < 2; ++ti)
                    V = fmaf(a, V, ut((t0 >> 5) + 2 * j + ti, b) * S);
                continue;
            }
            for (int k = 0; k < 64; ++k) {
                const int t = t0 + j * 64 + k;
                float u = ut(t >> 5, b);
                if (pd[j]) u += du_at(t, b);
                V = fmaf(bet, V, u);
                if (wj) {
                    __syncthreads();
                    srow[e] = (V >= vt) ? vtb : zb;
                    __syncthreads();
                    float acc2 = 0.f;
                    for (int d = 0; d < Dc; ++d)
                        acc2 = fmaf((float)srow[d], Wout[(size_t)d * Dc + e], acc2);
                    size_t r = (size_t)t * Bc + b;
                    float base = pd[j] ? (float)dxR[r * Dc + e] : 0.f;
                    dxW[r * Dc + e] = (__bf16)(base + acc2);
                }
            }
        }
    }
}

// ---------------------------------------------------------------------------
// Output PLIF scan + K-frame mean, with inline hframe (rmsnorm of emb+dx)
// on dirty frames. Block = one (s,b) token row; thread owns 4 d's.
// ---------------------------------------------------------------------------
__global__ __launch_bounds__(256)
void out_scan2(const float* __restrict__ htok, const __bf16* __restrict__ dxf,
               const int* __restrict__ tok, const float* __restrict__ embed,
               const float* __restrict__ onw, const float* __restrict__ alpha_p,
               const float* __restrict__ obeta, const float* __restrict__ ovth,
               const int* __restrict__ flags, __bf16* __restrict__ decoded)
{
    const int tid = threadIdx.x;
    const int s = blockIdx.x, b = blockIdx.y;
    const float al = alpha_p[0];
    const f32x4 bet = ((const f32x4*)obeta)[tid];
    const f32x4 vt  = ((const f32x4*)ovth)[tid];
    f32x4 a = bet, S = {1.f, 1.f, 1.f, 1.f};
#pragma unroll
    for (int i = 0; i < 5; ++i) {
#pragma unroll
        for (int c = 0; c < 4; ++c) { S[c] *= 1.0f + a[c]; a[c] *= a[c]; }
    }

    const int t0 = s * Kc;
    const int tlo = (t0 >= 64) ? t0 - 64 : 0;
    bool dirty = false;
    for (int c = tlo >> 6; c <= (t0 + Kc - 1) >> 6; ++c)
        dirty = dirty || gate_or(flags, NLc, c);

    f32x4 V = {0,0,0,0}, sum = {0,0,0,0};
    if (!dirty) {
        for (int tk = (s >= 2 ? s - 2 : 0); tk < s; ++tk) {
            f32x4 h = ((const f32x4*)(htok + ((size_t)tk * Bc + b) * Dc))[tid];
#pragma unroll
            for (int c = 0; c < 4; ++c) V[c] = fmaf(a[c], V[c], al * h[c] * S[c]);
        }
        f32x4 h = ((const f32x4*)(htok + ((size_t)s * Bc + b) * Dc))[tid];
        for (int k = 0; k < Kc; ++k) {
#pragma unroll
            for (int c = 0; c < 4; ++c) {
                V[c] = fmaf(bet[c], V[c], al * h[c]);
                sum[c] += (V[c] >= vt[c]) ? vt[c] : 0.f;
            }
        }
    } else {
        const f32x4 wv = ((const f32x4*)onw)[tid];
        __shared__ float red[4];
        for (int t = tlo; t < t0 + Kc; ++t) {
            const bool g = gate_or(flags, NLc, t >> 6);
            f32x4 h;
            if (g) {
                size_t r = (size_t)t * Bc + b;
                int id = tok[b * Sc + (t >> 5)];
                f32x4 v = ((const f32x4*)(embed + (size_t)id * Dc))[tid];
                bf16x4 dv = ((const bf16x4*)(dxf + r * Dc))[tid];
#pragma unroll
                for (int c = 0; c < 4; ++c) v[c] += (float)dv[c];
                float ss = v[0]*v[0] + v[1]*v[1] + v[2]*v[2] + v[3]*v[3];
#pragma unroll
                for (int off = 32; off >= 1; off >>= 1) ss += __shfl_down(ss, off);
                if ((tid & 63) == 0) red[tid >> 6] = ss;
                __syncthreads();
                float tot = red[0] + red[1] + red[2] + red[3];
                __syncthreads();
                float sc = rsqrtf(tot * (1.0f / Dc) + 1e-6f);
#pragma unroll
                for (int c = 0; c < 4; ++c) h[c] = v[c] * sc * wv[c];
            } else {
                h = ((const f32x4*)(htok + ((size_t)(t >> 5) * Bc + b) * Dc))[tid];
            }
#pragma unroll
            for (int c = 0; c < 4; ++c) {
                V[c] = fmaf(bet[c], V[c], al * h[c]);
                if (t >= t0) sum[c] += (V[c] >= vt[c]) ? vt[c] : 0.f;
            }
        }
    }
    bf16x4 o;
#pragma unroll
    for (int c = 0; c < 4; ++c) o[c] = (__bf16)(sum[c] * (1.0f / 32.0f));
    ((bf16x4*)(decoded + ((size_t)b * Sc + s) * Dc))[tid] = o;
}

// ---------------------------------------------------------------------------
// Fused prep: [0,4096) W_in -> wT_in (transpose+cast); [4096,4608) token rows:
// xtok = bf16(emb[id]), h_tok = rmsnorm(emb[id])*out_norm_w; r==0 zeroes flags.
// ---------------------------------------------------------------------------
__global__ __launch_bounds__(256)
void prep(const float* __restrict__ W_in, const float* __restrict__ embed,
          const int* __restrict__ tok, const float* __restrict__ onw,
          __bf16* __restrict__ wT_in, __bf16* __restrict__ xtok,
          float* __restrict__ h_tok, int* __restrict__ flags)
{
    const int blk = blockIdx.x;
    const int tid = threadIdx.x;
    if (blk < 4096) {
        __shared__ float tile[32][33];
        const int mat = blk >> 10;
        const int t2  = blk & 1023;
        const int d0  = (t2 & 31) * 32, e0 = (t2 >> 5) * 32;
        const float* Wm = W_in + (size_t)mat * Dc * Dc;
        __bf16*      Wo = wT_in + (size_t)mat * Dc * Dc;
        const int tx = tid & 31, ty = tid >> 5;
#pragma unroll
        for (int i = 0; i < 4; ++i)
            tile[ty + i*8][tx] = Wm[(size_t)(d0 + ty + i*8) * Dc + e0 + tx];
        __syncthreads();
        const int txp = tid & 15, tyw = tid >> 4;
#pragma unroll
        for (int i = 0; i < 2; ++i) {
            int r = tyw + 16 * i;
            bf16x2 o;
            o[0] = (__bf16)tile[2*txp][r];
            o[1] = (__bf16)tile[2*txp + 1][r];
            *(bf16x2*)(&Wo[(size_t)(e0 + r) * Dc + d0 + 2*txp]) = o;
        }
    } else {
        const int r = blk - 4096;           // r = s*Bc + b
        if (r == 0) { flags[tid] = 0; flags[tid + 256] = 0; }
        const int s = r >> 1, b = r & 1;
        const int id = tok[b * Sc + s];
        const f32x4 v = ((const f32x4*)(embed + (size_t)id * Dc))[tid];
        float ss = v[0]*v[0] + v[1]*v[1] + v[2]*v[2] + v[3]*v[3];
#pragma unroll
        for (int off = 32; off >= 1; off >>= 1) ss += __shfl_down(ss, off);
        __shared__ float red[4];
        if ((tid & 63) == 0) red[tid >> 6] = ss;
        __syncthreads();
        float tot = red[0] + red[1] + red[2] + red[3];
        float sc = rsqrtf(tot * (1.0f / Dc) + 1e-6f);
        const f32x4 wv = ((const f32x4*)onw)[tid];
        bf16x4 o; o[0]=(__bf16)v[0]; o[1]=(__bf16)v[1]; o[2]=(__bf16)v[2]; o[3]=(__bf16)v[3];
        ((bf16x4*)(xtok + (size_t)r * Dc))[tid] = o;
        f32x4 h = {v[0]*sc*wv[0], v[1]*sc*wv[1], v[2]*sc*wv[2], v[3]*sc*wv[3]};
        ((f32x4*)(h_tok + (size_t)r * Dc))[tid] = h;
    }
}

// RMSNorm over D=1024 per row -> bf16
__global__ __launch_bounds__(256)
void rmsnorm_rows(const float* __restrict__ in, const float* __restrict__ w,
                  __bf16* __restrict__ outb)
{
    const int r = blockIdx.x;
    const int tid = threadIdx.x;
    const f32x4 v = ((const f32x4*)(in + (size_t)r * Dc))[tid];
    float ss = v[0]*v[0] + v[1]*v[1] + v[2]*v[2] + v[3]*v[3];
#pragma unroll
    for (int off = 32; off >= 1; off >>= 1) ss += __shfl_down(ss, off);
    __shared__ float red[4];
    if ((tid & 63) == 0) red[tid >> 6] = ss;
    __syncthreads();
    float tot = red[0] + red[1] + red[2] + red[3];
    float sc = rsqrtf(tot * (1.0f / Dc) + 1e-6f);
    const f32x4 wv = ((const f32x4*)w)[tid];
    bf16x4 o;
    o[0]=(__bf16)(v[0]*sc*wv[0]); o[1]=(__bf16)(v[1]*sc*wv[1]);
    o[2]=(__bf16)(v[2]*sc*wv[2]); o[3]=(__bf16)(v[3]*sc*wv[3]);
    ((bf16x4*)(outb + (size_t)r * Dc))[tid] = o;
}

// ---------------------------------------------------------------------------
extern "C" void kernel_launch(void* const* d_in, const int* in_sizes, int n_in,
                              void* d_out, int out_size, void* d_ws, size_t ws_size,
                              hipStream_t stream)
{
    const int*   token_ids  = (const int*)  d_in[0];
    const float* embed      = (const float*)d_in[1];
    const float* W_in       = (const float*)d_in[2];
    const float* W_out      = (const float*)d_in[3];
    const float* layer_beta = (const float*)d_in[4];
    const float* layer_vth  = (const float*)d_in[5];
    const float* out_norm_w = (const float*)d_in[6];
    const float* out_beta   = (const float*)d_in[7];
    const float* out_vth    = (const float*)d_in[8];
    const float* out_alpha  = (const float*)d_in[9];
    const float* decode_w   = (const float*)d_in[10];
    const float* decode_b   = (const float*)d_in[11];
    const float* li_norm_w  = (const float*)d_in[12];
    float* out = (float*)d_out;

    size_t off = 0;
    auto alloc = [&](size_t bytes) -> void* {
        void* p = (char*)d_ws + off;
        off += (bytes + 255) & ~(size_t)255;
        return p;
    };
    __bf16* dxA      = (__bf16*)alloc((size_t)Tc * Bc * Dc * 2);   // ping-pong dx
    __bf16* dxB      = (__bf16*)alloc((size_t)Tc * Bc * Dc * 2);
    __bf16* u_tokall = (__bf16*)alloc((size_t)Bc * Sc * UTS * 2);  // [512][4096]
    float*  h_tok    = (float*) alloc((size_t)Bc * Sc * Dc * 4);
    __bf16* xtok     = (__bf16*)alloc((size_t)Bc * Sc * Dc * 2);
    __bf16* wT_in    = (__bf16*)alloc((size_t)NLc * Dc * Dc * 2);
    __bf16* decoded  = (__bf16*)alloc((size_t)Bc * Sc * Dc * 2);
    float*  h2       = (float*) alloc((size_t)Bc * Sc * Dc * 4);
    __bf16* h2n      = (__bf16*)alloc((size_t)Bc * Sc * Dc * 2);
    int*    flags    = (int*)   alloc((size_t)NLc * NPANEL * 4);
    __bf16* dxbuf[2] = { dxA, dxB };

    // 1. fused prep (W_in transpose+cast, token rows, flag zeroing)
    prep<<<4608, 256, 0, stream>>>(W_in, embed, token_ids, out_norm_w,
                                   wT_in, xtok, h_tok, flags);

    // 2. all-layer token-level u in ONE GEMM
    gemm_bt<3, 64, 128, 0><<<dim3(UTS / 128, (Bc * Sc) / 64), 256, 0, stream>>>(
        xtok, wT_in, nullptr, Bc * Sc, UTS, Dc, nullptr, u_tokall, nullptr);

    // 3. SNN layers: one fused kernel each (scan + gated fallbacks in-kernel)
    for (int l = 0; l < NLc; ++l) {
        fused_layer<<<NSEG, 1024, 0, stream>>>(
            u_tokall + (size_t)l * Dc, W_in + (size_t)l * Dc * Dc,
            W_out + (size_t)l * Dc * Dc, layer_beta + (size_t)l * Dc,
            layer_vth + (size_t)l * Dc, dxbuf[l & 1], dxbuf[(l + 1) & 1],
            flags, l);
    }
    __bf16* dxf = dxbuf[NLc & 1];

    // 4. decode head
    out_scan2<<<dim3(Sc, Bc), 256, 0, stream>>>(
        h_tok, dxf, token_ids, embed, out_norm_w, out_alpha, out_beta, out_vth,
        flags, decoded);
    gemm_bt<2, 64, 64, 1><<<dim3(Dc / 64, (Bc * Sc) / 64), 256, 0, stream>>>(
        decoded, nullptr, decode_w, Bc * Sc, Dc, Dc, h2, nullptr, decode_b);
    rmsnorm_rows<<<Bc * Sc, 256, 0, stream>>>(h2, li_norm_w, h2n);
    gemm_bt<0, 64, 128, 1><<<dim3(Vc / 128, (Bc * Sc) / 64), 256, 0, stream>>>(
        h2n, nullptr, embed, Bc * Sc, Vc, Dc, out, nullptr, nullptr);
}

// Round 8
// 92.970 us; speedup vs baseline: 8.4964x; 1.1728x over previous
//
#include <hip/hip_runtime.h>

typedef __bf16 bf16x8 __attribute__((ext_vector_type(8)));
typedef __bf16 bf16x4 __attribute__((ext_vector_type(4)));
typedef __bf16 bf16x2 __attribute__((ext_vector_type(2)));
typedef float  f32x4  __attribute__((ext_vector_type(4)));

constexpr int Bc = 2, Sc = 256, Kc = 32, Tc = 8192, Dc = 1024, Vc = 6144, NLc = 4;
constexpr int NPANEL = (Tc * Bc) / 128;   // 128 chunks (64 frames x both batches)
constexpr int UTS = NLc * Dc;             // u_tok_all row stride (4096)

__device__ __forceinline__ void gload16(const void* g, void* l) {
    __builtin_amdgcn_global_load_lds(
        (const __attribute__((address_space(1))) unsigned int*)g,
        (__attribute__((address_space(3))) unsigned int*)l,
        16, 0, 0);
}

// bijective XCD-aware block swizzle (m204 variant)
__device__ __forceinline__ int xcd_swz(int lin, int nwg) {
    int q = nwg >> 3, r = nwg & 7;
    int x = lin & 7, o = lin >> 3;
    int base = (x < r) ? x * (q + 1) : r * (q + 1) + (x - r) * q;
    return base + o;
}

// OR of n flag arrays (stride NPANEL) at chunk p
__device__ __forceinline__ bool gate_or(const int* f, int n, int p) {
    bool g = false;
    for (int j = 0; j < n; ++j) g = g || (f[j * NPANEL + p] != 0);
    return g;
}

// ---------------------------------------------------------------------------
// GEMM: C[M][N] = A[M][K](bf16 rm) x BT[N][K](bf16 rm), BMxBN tile, BK=64,
// 4 waves (2x2), mfma 16x16x32, swizzled LDS via pre-swizzled global source
// + linear-dest global_load_lds (width 16).
// EPI 0: Cout=acc   EPI 2: Cout=acc+bias[col]   EPI 3: outb=bf16(acc)
// ---------------------------------------------------------------------------
template<int EPI, int BM, int BN>
__global__ __launch_bounds__(256)
void gemm_bt(const __bf16* __restrict__ A, const __bf16* __restrict__ BT,
             int M, int N, int Kd,
             float* __restrict__ Cout, __bf16* __restrict__ outb,
             const float* __restrict__ bias)
{
    constexpr int MI = BM / 32, NI = BN / 32;
    constexpr int CA = BM / 32, CB = BN / 32;
    __shared__ char lds[(BM + BN) * 128];
    char* As = lds;
    char* Bs = lds + BM * 128;
    const int tid  = threadIdx.x;
    const int lane = tid & 63;
    const int wid  = tid >> 6;
    const int wm   = wid & 1, wn = wid >> 1;

    const int nwg = gridDim.x * gridDim.y;
    const int lin = blockIdx.y * gridDim.x + blockIdx.x;
    const int swz = xcd_swz(lin, nwg);
    const int bn  = (swz % gridDim.x) * BN;
    const int bm  = (swz / gridDim.x) * BM;

    const __bf16* asrc[CA];
#pragma unroll
    for (int i = 0; i < CA; ++i) {
        int chunk = i * 256 + tid;
        int row = chunk >> 3, kc = chunk & 7;
        int kcs = kc ^ (row & 7);             // pre-swizzled global source
        asrc[i] = A + (size_t)(bm + row) * Kd + kcs * 8;
    }
    const __bf16* bsrc[CB];
#pragma unroll
    for (int i = 0; i < CB; ++i) {
        int chunk = i * 256 + tid;
        int row = chunk >> 3, kc = chunk & 7;
        int kcs = kc ^ (row & 7);
        bsrc[i] = BT + (size_t)(bn + row) * Kd + kcs * 8;
    }

    f32x4 acc[MI][NI] = {};

    for (int kt = 0; kt < Kd; kt += 64) {
#pragma unroll
        for (int i = 0; i < CA; ++i)
            gload16(asrc[i] + kt, As + (i * 256 + tid) * 16);
#pragma unroll
        for (int i = 0; i < CB; ++i)
            gload16(bsrc[i] + kt, Bs + (i * 256 + tid) * 16);
        __syncthreads();
#pragma unroll
        for (int kk = 0; kk < 2; ++kk) {
            const int ko = kk * 64 + ((lane >> 4) << 4);
            bf16x8 af[MI], bfr[NI];
#pragma unroll
            for (int mi = 0; mi < MI; ++mi) {
                int row = wm * (BM / 2) + mi * 16 + (lane & 15);
                af[mi] = *(const bf16x8*)(As + row * 128 + (ko ^ ((row & 7) << 4)));
            }
#pragma unroll
            for (int ni = 0; ni < NI; ++ni) {
                int row = wn * (BN / 2) + ni * 16 + (lane & 15);
                bfr[ni] = *(const bf16x8*)(Bs + row * 128 + (ko ^ ((row & 7) << 4)));
            }
#pragma unroll
            for (int mi = 0; mi < MI; ++mi)
#pragma unroll
                for (int ni = 0; ni < NI; ++ni)
                    acc[mi][ni] = __builtin_amdgcn_mfma_f32_16x16x32_bf16(
                        af[mi], bfr[ni], acc[mi][ni], 0, 0, 0);
        }
        __syncthreads();
    }

    const int cc = lane & 15, cr = (lane >> 4) * 4;
#pragma unroll
    for (int mi = 0; mi < MI; ++mi) {
#pragma unroll
        for (int ni = 0; ni < NI; ++ni) {
            int gcol = bn + wn * (BN / 2) + ni * 16 + cc;
#pragma unroll
            for (int r = 0; r < 4; ++r) {
                int grow = bm + wm * (BM / 2) + mi * 16 + cr + r;
                size_t idx = (size_t)grow * N + gcol;
                float v = acc[mi][ni][r];
                if (EPI == 0)      Cout[idx] = v;
                else if (EPI == 2) Cout[idx] = v + bias[gcol];
                else               outb[idx] = (__bf16)v;
            }
        }
    }
}

// ---------------------------------------------------------------------------
// Chunk-parallel fused per-layer SNN step: one block per 64-frame chunk
// (1024 threads = all e; b looped). Warm-up = previous chunk only (beta^64
// below f32 ulp — exact truncation used throughout). Clean chunks: closed
// form (V32 = a32*V + u*S32, monotone -> endpoint check). Dirty/flagged
// fallback: in-kernel VALU du/dx (rare; correctness-only). dx ping-pong.
// ---------------------------------------------------------------------------
__global__ __launch_bounds__(1024)
void fused_layer(const __bf16* __restrict__ utok, const float* __restrict__ Win,
                 const float* __restrict__ Wout, const float* __restrict__ beta,
                 const float* __restrict__ vth, const __bf16* __restrict__ dxR,
                 __bf16* __restrict__ dxW, int* __restrict__ flags_all, int l)
{
    const int e  = threadIdx.x;
    const int p  = blockIdx.x;            // chunk index
    const int t0 = p * 64;
    const float bet = beta[e], vt = vth[e];
    float a = bet, S = 1.0f;
#pragma unroll
    for (int i = 0; i < 5; ++i) { S = S * (1.0f + a); a = a * a; }
    int* flags_l = flags_all + l * NPANEL;

    __shared__ int fm;
    __shared__ __bf16 srow[Dc];
    if (e == 0) fm = 0;
    __syncthreads();

    const bool pd  = gate_or(flags_all, l, p);
    const bool pdw = (p > 0) && gate_or(flags_all, l, p - 1);

    auto ut = [&](int tk, int b) -> float {
        return (float)utok[((size_t)tk * Bc + b) * UTS + e];
    };
    auto du_at = [&](int t, int b) -> float {   // uniform-call only
        __syncthreads();
        srow[e] = dxR[((size_t)t * Bc + b) * Dc + e];
        __syncthreads();
        float acc = 0.f;
        for (int d = 0; d < Dc; ++d)
            acc = fmaf((float)srow[d], Win[(size_t)d * Dc + e], acc);
        return acc;
    };

    // ---- phase 1: this chunk's spike flag
    bool spike = false;
    for (int b = 0; b < Bc; ++b) {
        float V = 0.f;
        if (p > 0) {
            if (!pdw) {
                for (int ti = 0; ti < 2; ++ti)
                    V = fmaf(a, V, ut(2 * p - 2 + ti, b) * S);
            } else {
                for (int t = t0 - 64; t < t0; ++t)
                    V = fmaf(bet, V, ut(t >> 5, b) + du_at(t, b));
            }
        }
        if (!pd) {
            for (int ti = 0; ti < 2; ++ti) {
                const float u = ut(2 * p + ti, b);
                float V1 = fmaf(bet, V, u);      // first step of token window
                V = fmaf(a, V, u * S);           // after 32 steps
                spike = spike || (fmaxf(V1, V) >= vt);   // monotone => endpoints
            }
        } else {
            for (int k = 0; k < 64; ++k) {
                const int t = t0 + k;
                V = fmaf(bet, V, ut(t >> 5, b) + du_at(t, b));
                spike = spike || (V >= vt);
            }
        }
    }
    if (__any(spike) && (e & 63) == 0) atomicOr(&fm, 1);
    __syncthreads();
    const bool f = (fm != 0);
    if (e == 0) flags_l[p] = f ? 1 : 0;
    if (!f) {
        if (pd) {   // dirty chunk that didn't spike this layer: copy-forward
            for (int rr = 0; rr < 128; ++rr)
                dxW[(size_t)(t0 * Bc + rr) * Dc + e] =
                    dxR[(size_t)(t0 * Bc + rr) * Dc + e];
        }
        return;
    }

    // ---- phase 2 (rare): stepwise spike recompute + dx update
    const __bf16 vtb = (__bf16)vt, zb = (__bf16)0.f;
    for (int b = 0; b < Bc; ++b) {
        float V = 0.f;
        if (p > 0) {
            if (!pdw) {
                for (int ti = 0; ti < 2; ++ti)
                    V = fmaf(a, V, ut(2 * p - 2 + ti, b) * S);
            } else {
                for (int t = t0 - 64; t < t0; ++t)
                    V = fmaf(bet, V, ut(t >> 5, b) + du_at(t, b));
            }
        }
        for (int k = 0; k < 64; ++k) {
            const int t = t0 + k;
            float u = ut(t >> 5, b);
            if (pd) u += du_at(t, b);
            V = fmaf(bet, V, u);
            __syncthreads();
            srow[e] = (V >= vt) ? vtb : zb;
            __syncthreads();
            float acc2 = 0.f;
            for (int d = 0; d < Dc; ++d)
                acc2 = fmaf((float)srow[d], Wout[(size_t)d * Dc + e], acc2);
            size_t r = (size_t)t * Bc + b;
            float base = pd ? (float)dxR[r * Dc + e] : 0.f;
            dxW[r * Dc + e] = (__bf16)(base + acc2);
        }
    }
}

// ---------------------------------------------------------------------------
// Output PLIF scan + K-frame mean, inline hframe (rmsnorm of emb+dx) on
// dirty frames. Block = one (s,b) token row; thread owns 4 d's.
// ---------------------------------------------------------------------------
__global__ __launch_bounds__(256)
void out_scan2(const float* __restrict__ htok, const __bf16* __restrict__ dxf,
               const int* __restrict__ tok, const float* __restrict__ embed,
               const float* __restrict__ onw, const float* __restrict__ alpha_p,
               const float* __restrict__ obeta, const float* __restrict__ ovth,
               const int* __restrict__ flags, __bf16* __restrict__ decoded)
{
    const int tid = threadIdx.x;
    const int s = blockIdx.x, b = blockIdx.y;
    const float al = alpha_p[0];
    const f32x4 bet = ((const f32x4*)obeta)[tid];
    const f32x4 vt  = ((const f32x4*)ovth)[tid];
    f32x4 a = bet, S = {1.f, 1.f, 1.f, 1.f};
#pragma unroll
    for (int i = 0; i < 5; ++i) {
#pragma unroll
        for (int c = 0; c < 4; ++c) { S[c] *= 1.0f + a[c]; a[c] *= a[c]; }
    }

    const int t0 = s * Kc;
    const int tlo = (t0 >= 64) ? t0 - 64 : 0;
    bool dirty = false;
    for (int c = tlo >> 6; c <= (t0 + Kc - 1) >> 6; ++c)
        dirty = dirty || gate_or(flags, NLc, c);

    f32x4 V = {0,0,0,0}, sum = {0,0,0,0};
    if (!dirty) {
        for (int tk = (s >= 2 ? s - 2 : 0); tk < s; ++tk) {
            f32x4 h = ((const f32x4*)(htok + ((size_t)tk * Bc + b) * Dc))[tid];
#pragma unroll
            for (int c = 0; c < 4; ++c) V[c] = fmaf(a[c], V[c], al * h[c] * S[c]);
        }
        f32x4 h = ((const f32x4*)(htok + ((size_t)s * Bc + b) * Dc))[tid];
        for (int k = 0; k < Kc; ++k) {
#pragma unroll
            for (int c = 0; c < 4; ++c) {
                V[c] = fmaf(bet[c], V[c], al * h[c]);
                sum[c] += (V[c] >= vt[c]) ? vt[c] : 0.f;
            }
        }
    } else {
        const f32x4 wv = ((const f32x4*)onw)[tid];
        __shared__ float red[4];
        for (int t = tlo; t < t0 + Kc; ++t) {
            const bool g = gate_or(flags, NLc, t >> 6);
            f32x4 h;
            if (g) {
                size_t r = (size_t)t * Bc + b;
                int id = tok[b * Sc + (t >> 5)];
                f32x4 v = ((const f32x4*)(embed + (size_t)id * Dc))[tid];
                bf16x4 dv = ((const bf16x4*)(dxf + r * Dc))[tid];
#pragma unroll
                for (int c = 0; c < 4; ++c) v[c] += (float)dv[c];
                float ss = v[0]*v[0] + v[1]*v[1] + v[2]*v[2] + v[3]*v[3];
#pragma unroll
                for (int off = 32; off >= 1; off >>= 1) ss += __shfl_down(ss, off);
                if ((tid & 63) == 0) red[tid >> 6] = ss;
                __syncthreads();
                float tot = red[0] + red[1] + red[2] + red[3];
                __syncthreads();
                float sc = rsqrtf(tot * (1.0f / Dc) + 1e-6f);
#pragma unroll
                for (int c = 0; c < 4; ++c) h[c] = v[c] * sc * wv[c];
            } else {
                h = ((const f32x4*)(htok + ((size_t)(t >> 5) * Bc + b) * Dc))[tid];
            }
#pragma unroll
            for (int c = 0; c < 4; ++c) {
                V[c] = fmaf(bet[c], V[c], al * h[c]);
                if (t >= t0) sum[c] += (V[c] >= vt[c]) ? vt[c] : 0.f;
            }
        }
    }
    bf16x4 o;
#pragma unroll
    for (int c = 0; c < 4; ++c) o[c] = (__bf16)(sum[c] * (1.0f / 32.0f));
    ((bf16x4*)(decoded + ((size_t)b * Sc + s) * Dc))[tid] = o;
}

// ---------------------------------------------------------------------------
// Fused prep, role-partitioned by flat blockIdx.x:
//  [0,4096)     W_in -> wT_in (bf16 transpose, 32x32 tiles)
//  [4096,7168)  embed -> emb_bf (8 elems/thread)
//  [7168,7680)  decode_w -> decw_bf
//  [7680,8192)  token rows: xtok = bf16(emb[id]); h_tok = rmsnorm(emb[id])*onw
//               (r==0 also zeroes the flag array)
// ---------------------------------------------------------------------------
__global__ __launch_bounds__(256)
void prep(const float* __restrict__ W_in, const float* __restrict__ embed,
          const float* __restrict__ decode_w, const int* __restrict__ tok,
          const float* __restrict__ onw, __bf16* __restrict__ wT_in,
          __bf16* __restrict__ emb_bf, __bf16* __restrict__ decw_bf,
          __bf16* __restrict__ xtok, float* __restrict__ h_tok,
          int* __restrict__ flags)
{
    const int blk = blockIdx.x;
    const int tid = threadIdx.x;
    if (blk < 4096) {
        __shared__ float tile[32][33];
        const int mat = blk >> 10;
        const int t2  = blk & 1023;
        const int d0  = (t2 & 31) * 32, e0 = (t2 >> 5) * 32;
        const float* Wm = W_in + (size_t)mat * Dc * Dc;
        __bf16*      Wo = wT_in + (size_t)mat * Dc * Dc;
        const int tx = tid & 31, ty = tid >> 5;
#pragma unroll
        for (int i = 0; i < 4; ++i)
            tile[ty + i*8][tx] = Wm[(size_t)(d0 + ty + i*8) * Dc + e0 + tx];
        __syncthreads();
        const int txp = tid & 15, tyw = tid >> 4;
#pragma unroll
        for (int i = 0; i < 2; ++i) {
            int r = tyw + 16 * i;
            bf16x2 o;
            o[0] = (__bf16)tile[2*txp][r];
            o[1] = (__bf16)tile[2*txp + 1][r];
            *(bf16x2*)(&Wo[(size_t)(e0 + r) * Dc + d0 + 2*txp]) = o;
        }
    } else if (blk < 7680) {                  // casts (8 elems/thread)
        const float* src; __bf16* dst; int idx;
        if (blk < 7168) { src = embed;    dst = emb_bf;  idx = (blk - 4096) * 256 + tid; }
        else            { src = decode_w; dst = decw_bf; idx = (blk - 7168) * 256 + tid; }
        const f32x4* pp = (const f32x4*)src + (size_t)idx * 2;
        f32x4 v0 = pp[0], v1 = pp[1];
        bf16x8 o;
        o[0]=(__bf16)v0[0]; o[1]=(__bf16)v0[1]; o[2]=(__bf16)v0[2]; o[3]=(__bf16)v0[3];
        o[4]=(__bf16)v1[0]; o[5]=(__bf16)v1[1]; o[6]=(__bf16)v1[2]; o[7]=(__bf16)v1[3];
        ((bf16x8*)dst)[idx] = o;
    } else {
        const int r = blk - 7680;             // r = s*Bc + b
        if (r == 0) { flags[tid] = 0; flags[tid + 256] = 0; }
        const int s = r >> 1, b = r & 1;
        const int id = tok[b * Sc + s];
        const f32x4 v = ((const f32x4*)(embed + (size_t)id * Dc))[tid];
        float ss = v[0]*v[0] + v[1]*v[1] + v[2]*v[2] + v[3]*v[3];
#pragma unroll
        for (int off = 32; off >= 1; off >>= 1) ss += __shfl_down(ss, off);
        __shared__ float red[4];
        if ((tid & 63) == 0) red[tid >> 6] = ss;
        __syncthreads();
        float tot = red[0] + red[1] + red[2] + red[3];
        float sc = rsqrtf(tot * (1.0f / Dc) + 1e-6f);
        const f32x4 wv = ((const f32x4*)onw)[tid];
        bf16x4 o; o[0]=(__bf16)v[0]; o[1]=(__bf16)v[1]; o[2]=(__bf16)v[2]; o[3]=(__bf16)v[3];
        ((bf16x4*)(xtok + (size_t)r * Dc))[tid] = o;
        f32x4 h = {v[0]*sc*wv[0], v[1]*sc*wv[1], v[2]*sc*wv[2], v[3]*sc*wv[3]};
        ((f32x4*)(h_tok + (size_t)r * Dc))[tid] = h;
    }
}

// RMSNorm over D=1024 per row -> bf16
__global__ __launch_bounds__(256)
void rmsnorm_rows(const float* __restrict__ in, const float* __restrict__ w,
                  __bf16* __restrict__ outb)
{
    const int r = blockIdx.x;
    const int tid = threadIdx.x;
    const f32x4 v = ((const f32x4*)(in + (size_t)r * Dc))[tid];
    float ss = v[0]*v[0] + v[1]*v[1] + v[2]*v[2] + v[3]*v[3];
#pragma unroll
    for (int off = 32; off >= 1; off >>= 1) ss += __shfl_down(ss, off);
    __shared__ float red[4];
    if ((tid & 63) == 0) red[tid >> 6] = ss;
    __syncthreads();
    float tot = red[0] + red[1] + red[2] + red[3];
    float sc = rsqrtf(tot * (1.0f / Dc) + 1e-6f);
    const f32x4 wv = ((const f32x4*)w)[tid];
    bf16x4 o;
    o[0]=(__bf16)(v[0]*sc*wv[0]); o[1]=(__bf16)(v[1]*sc*wv[1]);
    o[2]=(__bf16)(v[2]*sc*wv[2]); o[3]=(__bf16)(v[3]*sc*wv[3]);
    ((bf16x4*)(outb + (size_t)r * Dc))[tid] = o;
}

// ---------------------------------------------------------------------------
extern "C" void kernel_launch(void* const* d_in, const int* in_sizes, int n_in,
                              void* d_out, int out_size, void* d_ws, size_t ws_size,
                              hipStream_t stream)
{
    const int*   token_ids  = (const int*)  d_in[0];
    const float* embed      = (const float*)d_in[1];
    const float* W_in       = (const float*)d_in[2];
    const float* W_out      = (const float*)d_in[3];
    const float* layer_beta = (const float*)d_in[4];
    const float* layer_vth  = (const float*)d_in[5];
    const float* out_norm_w = (const float*)d_in[6];
    const float* out_beta   = (const float*)d_in[7];
    const float* out_vth    = (const float*)d_in[8];
    const float* out_alpha  = (const float*)d_in[9];
    const float* decode_w   = (const float*)d_in[10];
    const float* decode_b   = (const float*)d_in[11];
    const float* li_norm_w  = (const float*)d_in[12];
    float* out = (float*)d_out;

    size_t off = 0;
    auto alloc = [&](size_t bytes) -> void* {
        void* p = (char*)d_ws + off;
        off += (bytes + 255) & ~(size_t)255;
        return p;
    };
    __bf16* dxA      = (__bf16*)alloc((size_t)Tc * Bc * Dc * 2);   // ping-pong dx
    __bf16* dxB      = (__bf16*)alloc((size_t)Tc * Bc * Dc * 2);
    __bf16* u_tokall = (__bf16*)alloc((size_t)Bc * Sc * UTS * 2);  // [512][4096]
    float*  h_tok    = (float*) alloc((size_t)Bc * Sc * Dc * 4);
    __bf16* xtok     = (__bf16*)alloc((size_t)Bc * Sc * Dc * 2);
    __bf16* wT_in    = (__bf16*)alloc((size_t)NLc * Dc * Dc * 2);
    __bf16* emb_bf   = (__bf16*)alloc((size_t)Vc * Dc * 2);
    __bf16* decw_bf  = (__bf16*)alloc((size_t)Dc * Dc * 2);
    __bf16* decoded  = (__bf16*)alloc((size_t)Bc * Sc * Dc * 2);
    float*  h2       = (float*) alloc((size_t)Bc * Sc * Dc * 4);
    __bf16* h2n      = (__bf16*)alloc((size_t)Bc * Sc * Dc * 2);
    int*    flags    = (int*)   alloc((size_t)NLc * NPANEL * 4);
    __bf16* dxbuf[2] = { dxA, dxB };

    // 1. fused prep (W_in transpose+cast, embed/decw casts, token rows, flags)
    prep<<<8192, 256, 0, stream>>>(W_in, embed, decode_w, token_ids, out_norm_w,
                                   wT_in, emb_bf, decw_bf, xtok, h_tok, flags);

    // 2. all-layer token-level u in ONE GEMM
    gemm_bt<3, 64, 128><<<dim3(UTS / 128, (Bc * Sc) / 64), 256, 0, stream>>>(
        xtok, wT_in, Bc * Sc, UTS, Dc, nullptr, u_tokall, nullptr);

    // 3. SNN layers: chunk-parallel fused scan (gated fallbacks in-kernel)
    for (int l = 0; l < NLc; ++l) {
        fused_layer<<<NPANEL, 1024, 0, stream>>>(
            u_tokall + (size_t)l * Dc, W_in + (size_t)l * Dc * Dc,
            W_out + (size_t)l * Dc * Dc, layer_beta + (size_t)l * Dc,
            layer_vth + (size_t)l * Dc, dxbuf[l & 1], dxbuf[(l + 1) & 1],
            flags, l);
    }
    __bf16* dxf = dxbuf[NLc & 1];

    // 4. decode head
    out_scan2<<<dim3(Sc, Bc), 256, 0, stream>>>(
        h_tok, dxf, token_ids, embed, out_norm_w, out_alpha, out_beta, out_vth,
        flags, decoded);
    gemm_bt<2, 64, 128><<<dim3(Dc / 128, (Bc * Sc) / 64), 256, 0, stream>>>(
        decoded, decw_bf, Bc * Sc, Dc, Dc, h2, nullptr, decode_b);
    rmsnorm_rows<<<Bc * Sc, 256, 0, stream>>>(h2, li_norm_w, h2n);
    gemm_bt<0, 128, 128><<<dim3(Vc / 128, (Bc * Sc) / 128), 256, 0, stream>>>(
        h2n, emb_bf, Bc * Sc, Vc, Dc, out, nullptr, nullptr);
}